// Round 11
// baseline (235.145 us; speedup 1.0000x reference)
//
#include <hip/hip_runtime.h>
#include <hip/hip_bf16.h>
#include <math.h>

#define N_NODES 30000
#define NHEAD   4
#define HDIM    64
#define NTYPES  5
#define EPT     40000
#define TE      (NTYPES * EPT)
#define KDIM    256
#define NCAT    1792   // 1280 Ktil | 256 Q | 256 V

typedef __attribute__((ext_vector_type(8))) short short8;
typedef __attribute__((ext_vector_type(4))) float f32x4;

__device__ __forceinline__ unsigned short f2bf(float f) {
    __hip_bfloat16 h = __float2bfloat16(f);
    return *reinterpret_cast<unsigned short*>(&h);
}
__device__ __forceinline__ float bf2f(unsigned short u) {
    return __uint_as_float((unsigned)u << 16);
}

// async global->LDS, 16B per lane. LDS dest is wave-uniform base + lane*16 (linear).
__device__ __forceinline__ void gload16(const unsigned short* g, unsigned short* l) {
    __builtin_amdgcn_global_load_lds((const __attribute__((address_space(1))) void*)g,
                                     (__attribute__((address_space(3))) void*)l, 16, 0, 0);
}

// ---- init: zero deg ----
__global__ __launch_bounds__(256) void init_kernel(int* __restrict__ deg) {
    const int gid = blockIdx.x * blockDim.x + threadIdx.x;
    if (gid < N_NODES) deg[gid] = 0;
}

// ---- CSR build: histogram ----
__global__ __launch_bounds__(256) void hist_kernel(const int* __restrict__ etgt,
                                                   int* __restrict__ deg) {
    const int stride = gridDim.x * blockDim.x;
    for (int i = blockIdx.x * blockDim.x + threadIdx.x; i < TE; i += stride)
        atomicAdd(&deg[etgt[i]], 1);
}

// ---- CSR build: single-block exclusive scan over 30000 degrees ----
__global__ __launch_bounds__(1024) void scan_kernel(const int* __restrict__ deg,
                                                    int* __restrict__ off,
                                                    int* __restrict__ cursor) {
    __shared__ int sums[1024];
    const int t = threadIdx.x;
    int local[30];
    int s = 0;
    const int base = t * 30;
#pragma unroll
    for (int j = 0; j < 30; ++j) {
        const int idx = base + j;
        const int d = (idx < N_NODES) ? deg[idx] : 0;
        local[j] = d;
        s += d;
    }
    sums[t] = s;
    __syncthreads();
    for (int d = 1; d < 1024; d <<= 1) {
        const int v = (t >= d) ? sums[t - d] : 0;
        __syncthreads();
        sums[t] += v;
        __syncthreads();
    }
    int run = (t > 0) ? sums[t - 1] : 0;
#pragma unroll
    for (int j = 0; j < 30; ++j) {
        const int idx = base + j;
        if (idx < N_NODES) {
            off[idx] = run;
            cursor[idx] = run;
            run += local[j];
        }
    }
}

// ---- CSR build: scatter PACKED (src | t<<16) into per-target buckets ----
__global__ __launch_bounds__(256) void scatter_kernel(const int* __restrict__ etgt,
                                                      const int* __restrict__ esrc,
                                                      int* __restrict__ cursor,
                                                      int* __restrict__ perm) {
    const int stride = gridDim.x * blockDim.x;
    for (int e = blockIdx.x * blockDim.x + threadIdx.x; e < TE; e += stride) {
        const int pos = atomicAdd(&cursor[etgt[e]], 1);
        perm[pos] = esrc[e] | ((e / EPT) << 16);
    }
}

// ---- merged prep: [0,1792) weight_prep | [1792,9292) h2bf | [9292,9372) vrelT | [9372,9628) owb ----
__global__ __launch_bounds__(256) void prep_all(const float* __restrict__ kqv_w,
                                                const float* __restrict__ kqv_b,
                                                const float* __restrict__ k_rel,
                                                const float* __restrict__ p_rel,
                                                const float* __restrict__ h,
                                                const float* __restrict__ v_rel,
                                                const float* __restrict__ out_w,
                                                unsigned short* __restrict__ Wcat,
                                                float* __restrict__ bias_cat,
                                                unsigned short* __restrict__ hb,
                                                unsigned short* __restrict__ vrelT,
                                                unsigned short* __restrict__ Wob) {
    const int bid = blockIdx.x;
    const int tid = threadIdx.x;
    if (bid < 1792) {
        const int r = bid, f = tid;
        if (r < 1280) {
            const int t = r >> 8, hh = (r >> 6) & 3, d = r & 63;
            const float sc = 0.125f * p_rel[t * NHEAD + hh];
            float acc = 0.f;
#pragma unroll
            for (int fp = 0; fp < 64; ++fp)
                acc = fmaf(kqv_w[(size_t)(hh * 64 + fp) * 256 + f], k_rel[t * 4096 + fp * 64 + d], acc);
            Wcat[(size_t)r * 256 + f] = f2bf(acc * sc);
            if (f == 0) {
                float b = 0.f;
#pragma unroll
                for (int fp = 0; fp < 64; ++fp)
                    b = fmaf(kqv_b[hh * 64 + fp], k_rel[t * 4096 + fp * 64 + d], b);
                bias_cat[r] = b * sc;
            }
        } else {
            const int src_row = r - 1024;  // 1280->256 (Q), 1536->512 (V)
            Wcat[(size_t)r * 256 + f] = f2bf(kqv_w[(size_t)src_row * 256 + f]);
            if (f == 0) bias_cat[r] = kqv_b[src_row];
        }
    } else if (bid < 9292) {
        const int i = (bid - 1792) * 256 + tid;   // exactly 1,920,000 float4s
        const float4 v = ((const float4*)h)[i];
        ushort4 u;
        u.x = f2bf(v.x); u.y = f2bf(v.y); u.z = f2bf(v.z); u.w = f2bf(v.w);
        ((ushort4*)hb)[i] = u;
    } else if (bid < 9372) {
        const int idx = (bid - 9292) * 256 + tid;
        if (idx < 64 * 320) {
            const int f = idx / 320, k = idx - f * 320;
            vrelT[f * 320 + k] = f2bf(v_rel[(k >> 6) * 4096 + (k & 63) * 64 + f]);
        }
    } else {
        const int i = (bid - 9372) * 256 + tid;   // exactly 65,536
        Wob[i] = f2bf(out_w[i]);
    }
}

// ---- MFMA GEMM: Ccat[30000,1792](bf16) = hb[30000,256] @ Wcat^T + bias_cat ----
__global__ __launch_bounds__(256) void mfma_gemm(const unsigned short* __restrict__ hb,
                                                 const unsigned short* __restrict__ Wcat,
                                                 const float* __restrict__ bias_cat,
                                                 unsigned short* __restrict__ Ccat) {
    __shared__ unsigned short As[2][128 * 32];
    __shared__ unsigned short Bs[2][128 * 32];
    // bijective chunked swizzle over 3290 = 235*14 blocks, 8 XCDs (m204)
    const int orig = blockIdx.x;
    const int xcd = orig & 7, pos = orig >> 3;
    const int q = 3290 / 8, r = 3290 % 8;  // 411, 2
    const int wgid = (xcd < r ? xcd * (q + 1) : r * (q + 1) + (xcd - r) * q) + pos;
    const int brow0 = (wgid / 14) * 128;
    const int bcol0 = (wgid % 14) * 128;

    const int t = threadIdx.x;
    const int wid = t >> 6, lane = t & 63;
    const int wr = wid >> 1, wc = wid & 1;
    const int lrow = lane & 15, kb = lane >> 4;
    const int srow = lane >> 2;
    const int schunk = ((lane & 3) ^ ((lane >> 3) & 3)) * 8;   // staged (swizzled) chunk
    const int rchunk = (kb ^ ((lrow >> 1) & 3)) * 8;           // swizzled read chunk

    const int arow0 = min(brow0 + wid * 16 + srow, N_NODES - 1);
    const int arow1 = min(brow0 + 64 + wid * 16 + srow, N_NODES - 1);
    const int brw0 = bcol0 + wid * 16 + srow;        // always < 1792
    const int brw1 = bcol0 + 64 + wid * 16 + srow;

    auto stage = [&](int buf, int kt) {
        gload16(hb + (size_t)arow0 * KDIM + kt + schunk, &As[buf][wid * 512]);
        gload16(hb + (size_t)arow1 * KDIM + kt + schunk, &As[buf][2048 + wid * 512]);
        gload16(Wcat + (size_t)brw0 * KDIM + kt + schunk, &Bs[buf][wid * 512]);
        gload16(Wcat + (size_t)brw1 * KDIM + kt + schunk, &Bs[buf][2048 + wid * 512]);
    };

    f32x4 acc[4][4];
#pragma unroll
    for (int m = 0; m < 4; ++m)
#pragma unroll
        for (int n = 0; n < 4; ++n) acc[m][n] = (f32x4)0.f;

    stage(0, 0);
    __syncthreads();
    int cur = 0;
    for (int kt = 0; kt < KDIM; kt += 32) {
        if (kt + 32 < KDIM) stage(cur ^ 1, kt + 32);
        short8 af[4], bfr[4];
#pragma unroll
        for (int m = 0; m < 4; ++m)
            af[m] = *(const short8*)&As[cur][(wr * 64 + m * 16 + lrow) * 32 + rchunk];
#pragma unroll
        for (int n = 0; n < 4; ++n)
            bfr[n] = *(const short8*)&Bs[cur][(wc * 64 + n * 16 + lrow) * 32 + rchunk];
#pragma unroll
        for (int m = 0; m < 4; ++m)
#pragma unroll
            for (int n = 0; n < 4; ++n)
                acc[m][n] = __builtin_amdgcn_mfma_f32_16x16x32_bf16(af[m], bfr[n], acc[m][n], 0, 0, 0);
        __syncthreads();
        cur ^= 1;
    }

    // ---- LDS-transpose epilogue: dwordx4 C-stores ----
    unsigned short* Ts = &As[0][0];
    float bias4[4];
#pragma unroll
    for (int n = 0; n < 4; ++n) bias4[n] = bias_cat[bcol0 + wc * 64 + n * 16 + lrow];
    const int lrw = wr * 16 + kb * 4;
    const int lcw = wc * 64 + lrow;
#pragma unroll
    for (int m = 0; m < 4; ++m) {
        __syncthreads();
#pragma unroll
        for (int n = 0; n < 4; ++n)
#pragma unroll
            for (int v = 0; v < 4; ++v)
                Ts[(lrw + v) * 132 + lcw + n * 16] = f2bf(acc[m][n][v] + bias4[n]);
        __syncthreads();
#pragma unroll
        for (int rd = 0; rd < 2; ++rd) {
            const int lr = (t >> 4) + rd * 16;          // 0..31
            const int c0 = (t & 15) * 8;                // 0..120 step 8
            const int grow = brow0 + (lr >> 4) * 64 + m * 16 + (lr & 15);
            if (grow < N_NODES) {
                const uint2 lo = *(const uint2*)&Ts[lr * 132 + c0];
                const uint2 hi = *(const uint2*)&Ts[lr * 132 + c0 + 4];
                const uint4 o = make_uint4(lo.x, lo.y, hi.x, hi.y);
                *(uint4*)&Ccat[(size_t)grow * NCAT + bcol0 + c0] = o;
            }
        }
    }
}

// ---- fused edge pass: one wave per target, packed-src CSR walk, 2-stage pipeline.
// Pair k+1's perm read + 4 gathers issue BEFORE pair k's compute; the per-pair
// compute block is textually identical to round 10 (same FMA pattern, same
// sequential es adds) so numerics match round 10 exactly.
__global__ __launch_bounds__(256) void edge_fused(const unsigned short* __restrict__ Ccat,
                                                  const int* __restrict__ off,
                                                  const int* __restrict__ perm,
                                                  unsigned short* __restrict__ Acat) {
    const int wid = threadIdx.x >> 6, lane = threadIdx.x & 63;
    const int tgt = (blockIdx.x << 2) + wid;
    const int h = lane >> 4, f0 = (lane & 15) << 2;
    const int off0 = off[tgt];
    const int off1 = (tgt == N_NODES - 1) ? TE : off[tgt + 1];
    const ushort4 qu = *(const ushort4*)(Ccat + (size_t)tgt * NCAT + 1280 + (h << 6) + f0);
    const float qx = bf2f(qu.x), qy = bf2f(qu.y), qz = bf2f(qu.z), qw = bf2f(qu.w);
    const int voff = 1536 + (h << 6) + f0;
    float es = 0.f;
    float4 a0 = make_float4(0, 0, 0, 0), a1 = a0, a2 = a0, a3 = a0, a4 = a0;

    int i = off0;
    bool two = false;
    int ct0 = 0, ct1 = 0;
    ushort4 ku0, vu0, ku1, vu1;
    if (i < off1) {
        two = (i + 1 < off1);
        const int pk0 = perm[i];
        const int pk1 = two ? perm[i + 1] : pk0;
        const int s0 = pk0 & 0xFFFF; ct0 = pk0 >> 16;
        const int s1 = pk1 & 0xFFFF; ct1 = pk1 >> 16;
        const size_t rb0 = (size_t)s0 * NCAT, rb1 = (size_t)s1 * NCAT;
        ku0 = *(const ushort4*)(Ccat + rb0 + ((ct0 * 4 + h) << 6) + f0);
        vu0 = *(const ushort4*)(Ccat + rb0 + voff);
        ku1 = *(const ushort4*)(Ccat + rb1 + ((ct1 * 4 + h) << 6) + f0);
        vu1 = *(const ushort4*)(Ccat + rb1 + voff);
    }
    while (i < off1) {
        const int ni = i + (two ? 2 : 1);
        // ---- issue NEXT pair's loads before computing current pair ----
        bool ntwo = false;
        int nt0 = 0, nt1 = 0;
        ushort4 nku0, nvu0, nku1, nvu1;
        if (ni < off1) {
            ntwo = (ni + 1 < off1);
            const int pk0 = perm[ni];
            const int pk1 = ntwo ? perm[ni + 1] : pk0;
            const int s0 = pk0 & 0xFFFF; nt0 = pk0 >> 16;
            const int s1 = pk1 & 0xFFFF; nt1 = pk1 >> 16;
            const size_t rb0 = (size_t)s0 * NCAT, rb1 = (size_t)s1 * NCAT;
            nku0 = *(const ushort4*)(Ccat + rb0 + ((nt0 * 4 + h) << 6) + f0);
            nvu0 = *(const ushort4*)(Ccat + rb0 + voff);
            nku1 = *(const ushort4*)(Ccat + rb1 + ((nt1 * 4 + h) << 6) + f0);
            nvu1 = *(const ushort4*)(Ccat + rb1 + voff);
        }
        // ---- compute current pair (identical text to round 10) ----
        float p0 = qx * bf2f(ku0.x) + qy * bf2f(ku0.y) + qz * bf2f(ku0.z) + qw * bf2f(ku0.w);
        float p1 = qx * bf2f(ku1.x) + qy * bf2f(ku1.y) + qz * bf2f(ku1.z) + qw * bf2f(ku1.w);
        p0 += __shfl_xor(p0, 1); p1 += __shfl_xor(p1, 1);
        p0 += __shfl_xor(p0, 2); p1 += __shfl_xor(p1, 2);
        p0 += __shfl_xor(p0, 4); p1 += __shfl_xor(p1, 4);
        p0 += __shfl_xor(p0, 8); p1 += __shfl_xor(p1, 8);
        {
            const float ex = __expf(p0);
            es += ex;
            const float mx = ex * bf2f(vu0.x), my = ex * bf2f(vu0.y);
            const float mz = ex * bf2f(vu0.z), mw = ex * bf2f(vu0.w);
            if (ct0 == 0)      { a0.x += mx; a0.y += my; a0.z += mz; a0.w += mw; }
            else if (ct0 == 1) { a1.x += mx; a1.y += my; a1.z += mz; a1.w += mw; }
            else if (ct0 == 2) { a2.x += mx; a2.y += my; a2.z += mz; a2.w += mw; }
            else if (ct0 == 3) { a3.x += mx; a3.y += my; a3.z += mz; a3.w += mw; }
            else               { a4.x += mx; a4.y += my; a4.z += mz; a4.w += mw; }
        }
        if (two) {
            const float ex = __expf(p1);
            es += ex;
            const float mx = ex * bf2f(vu1.x), my = ex * bf2f(vu1.y);
            const float mz = ex * bf2f(vu1.z), mw = ex * bf2f(vu1.w);
            if (ct1 == 0)      { a0.x += mx; a0.y += my; a0.z += mz; a0.w += mw; }
            else if (ct1 == 1) { a1.x += mx; a1.y += my; a1.z += mz; a1.w += mw; }
            else if (ct1 == 2) { a2.x += mx; a2.y += my; a2.z += mz; a2.w += mw; }
            else if (ct1 == 3) { a3.x += mx; a3.y += my; a3.z += mz; a3.w += mw; }
            else               { a4.x += mx; a4.y += my; a4.z += mz; a4.w += mw; }
        }
        // ---- rotate pipeline state ----
        i = ni;
        two = ntwo; ct0 = nt0; ct1 = nt1;
        ku0 = nku0; vu0 = nvu0; ku1 = nku1; vu1 = nvu1;
    }

    const float inv = 1.f / (es + 1e-16f);
    const size_t rr = (size_t)tgt * NHEAD + h;
    unsigned short* base = Acat + rr * (NTYPES * HDIM) + f0;
    ushort4 u;
    u.x = f2bf(a0.x * inv); u.y = f2bf(a0.y * inv); u.z = f2bf(a0.z * inv); u.w = f2bf(a0.w * inv);
    *(ushort4*)(base + 0 * HDIM) = u;
    u.x = f2bf(a1.x * inv); u.y = f2bf(a1.y * inv); u.z = f2bf(a1.z * inv); u.w = f2bf(a1.w * inv);
    *(ushort4*)(base + 1 * HDIM) = u;
    u.x = f2bf(a2.x * inv); u.y = f2bf(a2.y * inv); u.z = f2bf(a2.z * inv); u.w = f2bf(a2.w * inv);
    *(ushort4*)(base + 2 * HDIM) = u;
    u.x = f2bf(a3.x * inv); u.y = f2bf(a3.y * inv); u.z = f2bf(a3.z * inv); u.w = f2bf(a3.w * inv);
    *(ushort4*)(base + 3 * HDIM) = u;
    u.x = f2bf(a4.x * inv); u.y = f2bf(a4.y * inv); u.z = f2bf(a4.z * inv); u.w = f2bf(a4.w * inv);
    *(ushort4*)(base + 4 * HDIM) = u;
}

// ---- MFMA epilogue GEMM: aggVb[120000,64](bf16) = gelu(Acat[120000,320] @ vrelT^T) ----
__global__ __launch_bounds__(256) void gemm_cat_mfma(const unsigned short* __restrict__ Acat,
                                                     const unsigned short* __restrict__ vrelT,
                                                     unsigned short* __restrict__ aggVb) {
    __shared__ unsigned short As[256 * 40];
    __shared__ unsigned short Bs[64 * 40];
    const int brow0 = blockIdx.x * 256;
    const int t = threadIdx.x;
    const int wid = t >> 6, lane = t & 63;
    const int lrow = lane & 15, kb = lane >> 4;
    const int r0 = t >> 2, q0 = (t & 3) * 8;

    f32x4 acc[4][4];
#pragma unroll
    for (int m = 0; m < 4; ++m)
#pragma unroll
        for (int n = 0; n < 4; ++n) acc[m][n] = (f32x4)0.f;

    for (int kt = 0; kt < 320; kt += 32) {
        uint4 a[4];
#pragma unroll
        for (int i = 0; i < 4; ++i) {
            const int row = min(brow0 + r0 + 64 * i, 120000 - 1);
            a[i] = *(const uint4*)(Acat + (size_t)row * 320 + kt + q0);
        }
        const uint4 b0 = *(const uint4*)(vrelT + (size_t)r0 * 320 + kt + q0);
        __syncthreads();
#pragma unroll
        for (int i = 0; i < 4; ++i)
            *(uint4*)&As[(r0 + 64 * i) * 40 + q0] = a[i];
        *(uint4*)&Bs[r0 * 40 + q0] = b0;
        __syncthreads();
        short8 af[4], bf_[4];
#pragma unroll
        for (int m = 0; m < 4; ++m)
            af[m] = *(const short8*)&As[(wid * 64 + m * 16 + lrow) * 40 + kb * 8];
#pragma unroll
        for (int n = 0; n < 4; ++n)
            bf_[n] = *(const short8*)&Bs[(n * 16 + lrow) * 40 + kb * 8];
#pragma unroll
        for (int m = 0; m < 4; ++m)
#pragma unroll
            for (int n = 0; n < 4; ++n)
                acc[m][n] = __builtin_amdgcn_mfma_f32_16x16x32_bf16(af[m], bf_[n], acc[m][n], 0, 0, 0);
    }

#pragma unroll
    for (int m = 0; m < 4; ++m) {
        const int gr0 = brow0 + wid * 64 + m * 16 + kb * 4;
#pragma unroll
        for (int v = 0; v < 4; ++v) {
            const int grow = gr0 + v;
            if (grow < 120000) {
#pragma unroll
                for (int n = 0; n < 4; ++n) {
                    const int gcol = n * 16 + lrow;
                    const float x = acc[m][n][v];
                    const float g = 0.5f * x * (1.f + erff(x * 0.7071067811865475f));
                    aggVb[(size_t)grow * 64 + gcol] = f2bf(g);
                }
            }
        }
    }
}

// ---- MFMA out GEMM: out[30000,256] = sa*(aggVb @ Wob^T + out_b) + sb*hb (bf16 residual) ----
__global__ __launch_bounds__(256) void gemm_out_mfma(const unsigned short* __restrict__ A,
                                                     const unsigned short* __restrict__ Wob,
                                                     const float* __restrict__ bias,
                                                     float* __restrict__ C,
                                                     const unsigned short* __restrict__ hres,
                                                     const float* __restrict__ skip) {
    __shared__ unsigned short As[128 * 40];
    __shared__ unsigned short Bs[128 * 40];
    const int brow0 = blockIdx.x * 128;
    const int bcol0 = blockIdx.y * 128;
    const int t = threadIdx.x;
    const int wid = t >> 6, lane = t & 63;
    const int wr = wid >> 1, wc = wid & 1;
    const int lrow = lane & 15, kb = lane >> 4;
    const int r0 = t >> 2, q0 = t & 3;
    const int r1 = (t + 256) >> 2, q1 = t & 3;

    f32x4 acc[4][4];
#pragma unroll
    for (int m = 0; m < 4; ++m)
#pragma unroll
        for (int n = 0; n < 4; ++n) acc[m][n] = (f32x4)0.f;

    for (int kt = 0; kt < 256; kt += 32) {
        const int ar0 = min(brow0 + r0, N_NODES - 1);
        const int ar1 = min(brow0 + r1, N_NODES - 1);
        const uint4 a0 = *(const uint4*)(A + (size_t)ar0 * 256 + kt + q0 * 8);
        const uint4 a1 = *(const uint4*)(A + (size_t)ar1 * 256 + kt + q1 * 8);
        const uint4 b0 = *(const uint4*)(Wob + (size_t)(bcol0 + r0) * 256 + kt + q0 * 8);
        const uint4 b1 = *(const uint4*)(Wob + (size_t)(bcol0 + r1) * 256 + kt + q1 * 8);
        __syncthreads();
        *(uint4*)&As[r0 * 40 + q0 * 8] = a0;
        *(uint4*)&As[r1 * 40 + q1 * 8] = a1;
        *(uint4*)&Bs[r0 * 40 + q0 * 8] = b0;
        *(uint4*)&Bs[r1 * 40 + q1 * 8] = b1;
        __syncthreads();
        short8 af[4], bf_[4];
#pragma unroll
        for (int m = 0; m < 4; ++m)
            af[m] = *(const short8*)&As[(wr * 64 + m * 16 + lrow) * 40 + kb * 8];
#pragma unroll
        for (int n = 0; n < 4; ++n)
            bf_[n] = *(const short8*)&Bs[(wc * 64 + n * 16 + lrow) * 40 + kb * 8];
#pragma unroll
        for (int m = 0; m < 4; ++m)
#pragma unroll
            for (int n = 0; n < 4; ++n)
                acc[m][n] = __builtin_amdgcn_mfma_f32_16x16x32_bf16(af[m], bf_[n], acc[m][n], 0, 0, 0);
    }

    const float s = skip[0];
    const float sa = 1.f / (1.f + expf(-s));
    const float sb = 1.f - sa;
    float bias4[4];
#pragma unroll
    for (int n = 0; n < 4; ++n) bias4[n] = bias[bcol0 + wc * 64 + n * 16 + lrow];
#pragma unroll
    for (int m = 0; m < 4; ++m) {
        const int gr0 = brow0 + wr * 64 + m * 16 + kb * 4;
#pragma unroll
        for (int v = 0; v < 4; ++v) {
            const int grow = gr0 + v;
            if (grow < N_NODES) {
#pragma unroll
                for (int n = 0; n < 4; ++n) {
                    const int gcol = bcol0 + wc * 64 + n * 16 + lrow;
                    const float val = acc[m][n][v] + bias4[n];
                    C[(size_t)grow * 256 + gcol] = sa * val + sb * bf2f(hres[(size_t)grow * 256 + gcol]);
                }
            }
        }
    }
}

extern "C" void kernel_launch(void* const* d_in, const int* in_sizes, int n_in,
                              void* d_out, int out_size, void* d_ws, size_t ws_size,
                              hipStream_t stream) {
    const float* h      = (const float*)d_in[0];
    const int*   esrc   = (const int*)d_in[1];
    const int*   etgt   = (const int*)d_in[2];
    const float* kqv_w  = (const float*)d_in[3];
    const float* kqv_b  = (const float*)d_in[4];
    const float* out_w  = (const float*)d_in[5];
    const float* out_b  = (const float*)d_in[6];
    const float* k_rel  = (const float*)d_in[7];
    const float* v_rel  = (const float*)d_in[8];
    const float* skip   = (const float*)d_in[9];
    const float* p_rel  = (const float*)d_in[10];
    float* out = (float*)d_out;

    // workspace layout (float-sized slots):
    float* ws = (float*)d_ws;
    unsigned short* Ccat     = (unsigned short*)ws;                 // 26,880,000 slots [0 .. 26.88M)
    int*            deg      = (int*)(ws + 26880000);               //     30,000 -> 26,910,000
    int*            off      = (int*)(ws + 26910000);               //     30,000 -> 26,940,000
    int*            cursor   = (int*)(ws + 26940000);               //     30,000 -> 26,970,000
    int*            perm     = (int*)(ws + 26970000);               //    200,000 -> 27,170,000
    unsigned short* aggVb    = (unsigned short*)(ws + 27170000);    // 3,840,000 slots -> 31,010,000
    unsigned short* Acat     = (unsigned short*)(ws + 31010000);    // 19,200,000 slots -> 50,210,000
    // LATE-READ buffers (consumed AFTER Acat is written) -> past Acat's end:
    unsigned short* vrelT    = (unsigned short*)(ws + 50210000);    // 10,240 slots -> 50,220,240
    unsigned short* Wob      = (unsigned short*)(ws + 50220240);    // 32,768 slots -> 50,253,008
    unsigned short* hb       = (unsigned short*)(ws + 50253008);    // 3,840,000 slots -> 54,093,008
    //   (hb moved OUT of Acat's span: now read by gemm_out_mfma as bf16 residual)
    // EARLY-DEAD aliases inside Acat's span (read only BEFORE edge_fused writes Acat):
    unsigned short* Wcat     = (unsigned short*)(ws + 45370000);    // 229,376 slots -> ends 45,599,376
    float*          bias_cat = ws + 45600000;                       // 1,792 -> ends 45,601,792 (< 50.21M ok)
    // total footprint: 54,093,008 float slots = 216.4 MB (round 3 proved >= 219.9 MB available)

    hipLaunchKernelGGL(init_kernel, dim3(118), dim3(256), 0, stream, deg);
    hipLaunchKernelGGL(hist_kernel, dim3(782), dim3(256), 0, stream, etgt, deg);
    hipLaunchKernelGGL(scan_kernel, dim3(1), dim3(1024), 0, stream, deg, off, cursor);
    hipLaunchKernelGGL(scatter_kernel, dim3(782), dim3(256), 0, stream, etgt, esrc, cursor, perm);
    hipLaunchKernelGGL(prep_all, dim3(9628), dim3(256), 0, stream,
                       kqv_w, kqv_b, k_rel, p_rel, h, v_rel, out_w,
                       Wcat, bias_cat, hb, vrelT, Wob);
    hipLaunchKernelGGL(mfma_gemm, dim3(3290), dim3(256), 0, stream,
                       hb, Wcat, bias_cat, Ccat);
    hipLaunchKernelGGL(edge_fused, dim3(N_NODES / 4), dim3(256), 0, stream,
                       Ccat, off, perm, Acat);
    hipLaunchKernelGGL(gemm_cat_mfma, dim3(469), dim3(256), 0, stream,
                       Acat, vrelT, aggVb);
    hipLaunchKernelGGL(gemm_out_mfma, dim3(235, 2), dim3(256), 0, stream,
                       aggVb, Wob, out_b, out, hb, skip);
}

// Round 12
// 234.001 us; speedup vs baseline: 1.0049x; 1.0049x over previous
//
#include <hip/hip_runtime.h>
#include <hip/hip_bf16.h>
#include <math.h>

#define N_NODES 30000
#define NHEAD   4
#define HDIM    64
#define NTYPES  5
#define EPT     40000
#define TE      (NTYPES * EPT)
#define KDIM    256
#define NCAT    1792   // 1280 Ktil | 256 Q | 256 V

typedef __attribute__((ext_vector_type(8))) short short8;
typedef __attribute__((ext_vector_type(4))) float f32x4;

__device__ __forceinline__ unsigned short f2bf(float f) {
    __hip_bfloat16 h = __float2bfloat16(f);
    return *reinterpret_cast<unsigned short*>(&h);
}
__device__ __forceinline__ float bf2f(unsigned short u) {
    return __uint_as_float((unsigned)u << 16);
}

// async global->LDS, 16B per lane. LDS dest is wave-uniform base + lane*16 (linear).
__device__ __forceinline__ void gload16(const unsigned short* g, unsigned short* l) {
    __builtin_amdgcn_global_load_lds((const __attribute__((address_space(1))) void*)g,
                                     (__attribute__((address_space(3))) void*)l, 16, 0, 0);
}

// ---- init: zero deg ----
__global__ __launch_bounds__(256) void init_kernel(int* __restrict__ deg) {
    const int gid = blockIdx.x * blockDim.x + threadIdx.x;
    if (gid < N_NODES) deg[gid] = 0;
}

// ---- CSR build: histogram ----
__global__ __launch_bounds__(256) void hist_kernel(const int* __restrict__ etgt,
                                                   int* __restrict__ deg) {
    const int stride = gridDim.x * blockDim.x;
    for (int i = blockIdx.x * blockDim.x + threadIdx.x; i < TE; i += stride)
        atomicAdd(&deg[etgt[i]], 1);
}

// ---- CSR build: single-block exclusive scan over 30000 degrees ----
__global__ __launch_bounds__(1024) void scan_kernel(const int* __restrict__ deg,
                                                    int* __restrict__ off,
                                                    int* __restrict__ cursor) {
    __shared__ int sums[1024];
    const int t = threadIdx.x;
    int local[30];
    int s = 0;
    const int base = t * 30;
#pragma unroll
    for (int j = 0; j < 30; ++j) {
        const int idx = base + j;
        const int d = (idx < N_NODES) ? deg[idx] : 0;
        local[j] = d;
        s += d;
    }
    sums[t] = s;
    __syncthreads();
    for (int d = 1; d < 1024; d <<= 1) {
        const int v = (t >= d) ? sums[t - d] : 0;
        __syncthreads();
        sums[t] += v;
        __syncthreads();
    }
    int run = (t > 0) ? sums[t - 1] : 0;
#pragma unroll
    for (int j = 0; j < 30; ++j) {
        const int idx = base + j;
        if (idx < N_NODES) {
            off[idx] = run;
            cursor[idx] = run;
            run += local[j];
        }
    }
}

// ---- CSR build: scatter PACKED (src | t<<16) into per-target buckets ----
__global__ __launch_bounds__(256) void scatter_kernel(const int* __restrict__ etgt,
                                                      const int* __restrict__ esrc,
                                                      int* __restrict__ cursor,
                                                      int* __restrict__ perm) {
    const int stride = gridDim.x * blockDim.x;
    for (int e = blockIdx.x * blockDim.x + threadIdx.x; e < TE; e += stride) {
        const int pos = atomicAdd(&cursor[etgt[e]], 1);
        perm[pos] = esrc[e] | ((e / EPT) << 16);
    }
}

// ---- merged prep: [0,1792) weight_prep | [1792,9292) h2bf | [9292,9372) vrelT | [9372,9628) owb ----
__global__ __launch_bounds__(256) void prep_all(const float* __restrict__ kqv_w,
                                                const float* __restrict__ kqv_b,
                                                const float* __restrict__ k_rel,
                                                const float* __restrict__ p_rel,
                                                const float* __restrict__ h,
                                                const float* __restrict__ v_rel,
                                                const float* __restrict__ out_w,
                                                unsigned short* __restrict__ Wcat,
                                                float* __restrict__ bias_cat,
                                                unsigned short* __restrict__ hb,
                                                unsigned short* __restrict__ vrelT,
                                                unsigned short* __restrict__ Wob) {
    const int bid = blockIdx.x;
    const int tid = threadIdx.x;
    if (bid < 1792) {
        const int r = bid, f = tid;
        if (r < 1280) {
            const int t = r >> 8, hh = (r >> 6) & 3, d = r & 63;
            const float sc = 0.125f * p_rel[t * NHEAD + hh];
            float acc = 0.f;
#pragma unroll
            for (int fp = 0; fp < 64; ++fp)
                acc = fmaf(kqv_w[(size_t)(hh * 64 + fp) * 256 + f], k_rel[t * 4096 + fp * 64 + d], acc);
            Wcat[(size_t)r * 256 + f] = f2bf(acc * sc);
            if (f == 0) {
                float b = 0.f;
#pragma unroll
                for (int fp = 0; fp < 64; ++fp)
                    b = fmaf(kqv_b[hh * 64 + fp], k_rel[t * 4096 + fp * 64 + d], b);
                bias_cat[r] = b * sc;
            }
        } else {
            const int src_row = r - 1024;  // 1280->256 (Q), 1536->512 (V)
            Wcat[(size_t)r * 256 + f] = f2bf(kqv_w[(size_t)src_row * 256 + f]);
            if (f == 0) bias_cat[r] = kqv_b[src_row];
        }
    } else if (bid < 9292) {
        const int i = (bid - 1792) * 256 + tid;   // exactly 1,920,000 float4s
        const float4 v = ((const float4*)h)[i];
        ushort4 u;
        u.x = f2bf(v.x); u.y = f2bf(v.y); u.z = f2bf(v.z); u.w = f2bf(v.w);
        ((ushort4*)hb)[i] = u;
    } else if (bid < 9372) {
        const int idx = (bid - 9292) * 256 + tid;
        if (idx < 64 * 320) {
            const int f = idx / 320, k = idx - f * 320;
            vrelT[f * 320 + k] = f2bf(v_rel[(k >> 6) * 4096 + (k & 63) * 64 + f]);
        }
    } else {
        const int i = (bid - 9372) * 256 + tid;   // exactly 65,536
        Wob[i] = f2bf(out_w[i]);
    }
}

// ---- MFMA GEMM: Ccat[30000,1792](bf16) = hb[30000,256] @ Wcat^T + bias_cat ----
__global__ __launch_bounds__(256) void mfma_gemm(const unsigned short* __restrict__ hb,
                                                 const unsigned short* __restrict__ Wcat,
                                                 const float* __restrict__ bias_cat,
                                                 unsigned short* __restrict__ Ccat) {
    __shared__ unsigned short As[2][128 * 32];
    __shared__ unsigned short Bs[2][128 * 32];
    // bijective chunked swizzle over 3290 = 235*14 blocks, 8 XCDs (m204)
    const int orig = blockIdx.x;
    const int xcd = orig & 7, pos = orig >> 3;
    const int q = 3290 / 8, r = 3290 % 8;  // 411, 2
    const int wgid = (xcd < r ? xcd * (q + 1) : r * (q + 1) + (xcd - r) * q) + pos;
    const int brow0 = (wgid / 14) * 128;
    const int bcol0 = (wgid % 14) * 128;

    const int t = threadIdx.x;
    const int wid = t >> 6, lane = t & 63;
    const int wr = wid >> 1, wc = wid & 1;
    const int lrow = lane & 15, kb = lane >> 4;
    const int srow = lane >> 2;
    const int schunk = ((lane & 3) ^ ((lane >> 3) & 3)) * 8;   // staged (swizzled) chunk
    const int rchunk = (kb ^ ((lrow >> 1) & 3)) * 8;           // swizzled read chunk

    const int arow0 = min(brow0 + wid * 16 + srow, N_NODES - 1);
    const int arow1 = min(brow0 + 64 + wid * 16 + srow, N_NODES - 1);
    const int brw0 = bcol0 + wid * 16 + srow;        // always < 1792
    const int brw1 = bcol0 + 64 + wid * 16 + srow;

    auto stage = [&](int buf, int kt) {
        gload16(hb + (size_t)arow0 * KDIM + kt + schunk, &As[buf][wid * 512]);
        gload16(hb + (size_t)arow1 * KDIM + kt + schunk, &As[buf][2048 + wid * 512]);
        gload16(Wcat + (size_t)brw0 * KDIM + kt + schunk, &Bs[buf][wid * 512]);
        gload16(Wcat + (size_t)brw1 * KDIM + kt + schunk, &Bs[buf][2048 + wid * 512]);
    };

    f32x4 acc[4][4];
#pragma unroll
    for (int m = 0; m < 4; ++m)
#pragma unroll
        for (int n = 0; n < 4; ++n) acc[m][n] = (f32x4)0.f;

    stage(0, 0);
    __syncthreads();
    int cur = 0;
    for (int kt = 0; kt < KDIM; kt += 32) {
        if (kt + 32 < KDIM) stage(cur ^ 1, kt + 32);
        short8 af[4], bfr[4];
#pragma unroll
        for (int m = 0; m < 4; ++m)
            af[m] = *(const short8*)&As[cur][(wr * 64 + m * 16 + lrow) * 32 + rchunk];
#pragma unroll
        for (int n = 0; n < 4; ++n)
            bfr[n] = *(const short8*)&Bs[cur][(wc * 64 + n * 16 + lrow) * 32 + rchunk];
#pragma unroll
        for (int m = 0; m < 4; ++m)
#pragma unroll
            for (int n = 0; n < 4; ++n)
                acc[m][n] = __builtin_amdgcn_mfma_f32_16x16x32_bf16(af[m], bfr[n], acc[m][n], 0, 0, 0);
        __syncthreads();
        cur ^= 1;
    }

    // ---- LDS-transpose epilogue: dwordx4 C-stores ----
    unsigned short* Ts = &As[0][0];
    float bias4[4];
#pragma unroll
    for (int n = 0; n < 4; ++n) bias4[n] = bias_cat[bcol0 + wc * 64 + n * 16 + lrow];
    const int lrw = wr * 16 + kb * 4;
    const int lcw = wc * 64 + lrow;
#pragma unroll
    for (int m = 0; m < 4; ++m) {
        __syncthreads();
#pragma unroll
        for (int n = 0; n < 4; ++n)
#pragma unroll
            for (int v = 0; v < 4; ++v)
                Ts[(lrw + v) * 132 + lcw + n * 16] = f2bf(acc[m][n][v] + bias4[n]);
        __syncthreads();
#pragma unroll
        for (int rd = 0; rd < 2; ++rd) {
            const int lr = (t >> 4) + rd * 16;          // 0..31
            const int c0 = (t & 15) * 8;                // 0..120 step 8
            const int grow = brow0 + (lr >> 4) * 64 + m * 16 + (lr & 15);
            if (grow < N_NODES) {
                const uint2 lo = *(const uint2*)&Ts[lr * 132 + c0];
                const uint2 hi = *(const uint2*)&Ts[lr * 132 + c0 + 4];
                const uint4 o = make_uint4(lo.x, lo.y, hi.x, hi.y);
                *(uint4*)&Ccat[(size_t)grow * NCAT + bcol0 + c0] = o;
            }
        }
    }
}

// ---- fused edge pass: one wave per target, packed-src CSR walk.
// EXACT round-10 text (unroll-2, paired gathers, sequential es adds) — the
// round-11 2-stage rotation regressed (VALU copies > latency hidden).
__global__ __launch_bounds__(256) void edge_fused(const unsigned short* __restrict__ Ccat,
                                                  const int* __restrict__ off,
                                                  const int* __restrict__ perm,
                                                  unsigned short* __restrict__ Acat) {
    const int wid = threadIdx.x >> 6, lane = threadIdx.x & 63;
    const int tgt = (blockIdx.x << 2) + wid;
    const int h = lane >> 4, f0 = (lane & 15) << 2;
    const int off0 = off[tgt];
    const int off1 = (tgt == N_NODES - 1) ? TE : off[tgt + 1];
    const ushort4 qu = *(const ushort4*)(Ccat + (size_t)tgt * NCAT + 1280 + (h << 6) + f0);
    const float qx = bf2f(qu.x), qy = bf2f(qu.y), qz = bf2f(qu.z), qw = bf2f(qu.w);
    const int voff = 1536 + (h << 6) + f0;
    float es = 0.f;
    float4 a0 = make_float4(0, 0, 0, 0), a1 = a0, a2 = a0, a3 = a0, a4 = a0;
    int i = off0;
    while (i < off1) {
        const bool two = (i + 1 < off1);
        const int pk0 = perm[i];
        const int pk1 = two ? perm[i + 1] : pk0;
        const int s0 = pk0 & 0xFFFF, t0 = pk0 >> 16;
        const int s1 = pk1 & 0xFFFF, t1 = pk1 >> 16;
        const size_t rb0 = (size_t)s0 * NCAT, rb1 = (size_t)s1 * NCAT;
        // issue all 4 gathers before any compute (2x memory-level parallelism)
        const ushort4 ku0 = *(const ushort4*)(Ccat + rb0 + ((t0 * 4 + h) << 6) + f0);
        const ushort4 vu0 = *(const ushort4*)(Ccat + rb0 + voff);
        const ushort4 ku1 = *(const ushort4*)(Ccat + rb1 + ((t1 * 4 + h) << 6) + f0);
        const ushort4 vu1 = *(const ushort4*)(Ccat + rb1 + voff);
        float p0 = qx * bf2f(ku0.x) + qy * bf2f(ku0.y) + qz * bf2f(ku0.z) + qw * bf2f(ku0.w);
        float p1 = qx * bf2f(ku1.x) + qy * bf2f(ku1.y) + qz * bf2f(ku1.z) + qw * bf2f(ku1.w);
        p0 += __shfl_xor(p0, 1); p1 += __shfl_xor(p1, 1);
        p0 += __shfl_xor(p0, 2); p1 += __shfl_xor(p1, 2);
        p0 += __shfl_xor(p0, 4); p1 += __shfl_xor(p1, 4);
        p0 += __shfl_xor(p0, 8); p1 += __shfl_xor(p1, 8);
        {
            const float ex = __expf(p0);
            es += ex;
            const float mx = ex * bf2f(vu0.x), my = ex * bf2f(vu0.y);
            const float mz = ex * bf2f(vu0.z), mw = ex * bf2f(vu0.w);
            if (t0 == 0)      { a0.x += mx; a0.y += my; a0.z += mz; a0.w += mw; }
            else if (t0 == 1) { a1.x += mx; a1.y += my; a1.z += mz; a1.w += mw; }
            else if (t0 == 2) { a2.x += mx; a2.y += my; a2.z += mz; a2.w += mw; }
            else if (t0 == 3) { a3.x += mx; a3.y += my; a3.z += mz; a3.w += mw; }
            else              { a4.x += mx; a4.y += my; a4.z += mz; a4.w += mw; }
        }
        if (two) {
            const float ex = __expf(p1);
            es += ex;
            const float mx = ex * bf2f(vu1.x), my = ex * bf2f(vu1.y);
            const float mz = ex * bf2f(vu1.z), mw = ex * bf2f(vu1.w);
            if (t1 == 0)      { a0.x += mx; a0.y += my; a0.z += mz; a0.w += mw; }
            else if (t1 == 1) { a1.x += mx; a1.y += my; a1.z += mz; a1.w += mw; }
            else if (t1 == 2) { a2.x += mx; a2.y += my; a2.z += mz; a2.w += mw; }
            else if (t1 == 3) { a3.x += mx; a3.y += my; a3.z += mz; a3.w += mw; }
            else              { a4.x += mx; a4.y += my; a4.z += mz; a4.w += mw; }
        }
        i += two ? 2 : 1;
    }
    const float inv = 1.f / (es + 1e-16f);
    const size_t rr = (size_t)tgt * NHEAD + h;
    unsigned short* base = Acat + rr * (NTYPES * HDIM) + f0;
    ushort4 u;
    u.x = f2bf(a0.x * inv); u.y = f2bf(a0.y * inv); u.z = f2bf(a0.z * inv); u.w = f2bf(a0.w * inv);
    *(ushort4*)(base + 0 * HDIM) = u;
    u.x = f2bf(a1.x * inv); u.y = f2bf(a1.y * inv); u.z = f2bf(a1.z * inv); u.w = f2bf(a1.w * inv);
    *(ushort4*)(base + 1 * HDIM) = u;
    u.x = f2bf(a2.x * inv); u.y = f2bf(a2.y * inv); u.z = f2bf(a2.z * inv); u.w = f2bf(a2.w * inv);
    *(ushort4*)(base + 2 * HDIM) = u;
    u.x = f2bf(a3.x * inv); u.y = f2bf(a3.y * inv); u.z = f2bf(a3.z * inv); u.w = f2bf(a3.w * inv);
    *(ushort4*)(base + 3 * HDIM) = u;
    u.x = f2bf(a4.x * inv); u.y = f2bf(a4.y * inv); u.z = f2bf(a4.z * inv); u.w = f2bf(a4.w * inv);
    *(ushort4*)(base + 4 * HDIM) = u;
}

// ---- MFMA epilogue GEMM: aggVb[120000,64](bf16) = gelu(Acat[120000,320] @ vrelT^T) ----
__global__ __launch_bounds__(256) void gemm_cat_mfma(const unsigned short* __restrict__ Acat,
                                                     const unsigned short* __restrict__ vrelT,
                                                     unsigned short* __restrict__ aggVb) {
    __shared__ unsigned short As[256 * 40];
    __shared__ unsigned short Bs[64 * 40];
    const int brow0 = blockIdx.x * 256;
    const int t = threadIdx.x;
    const int wid = t >> 6, lane = t & 63;
    const int lrow = lane & 15, kb = lane >> 4;
    const int r0 = t >> 2, q0 = (t & 3) * 8;

    f32x4 acc[4][4];
#pragma unroll
    for (int m = 0; m < 4; ++m)
#pragma unroll
        for (int n = 0; n < 4; ++n) acc[m][n] = (f32x4)0.f;

    for (int kt = 0; kt < 320; kt += 32) {
        uint4 a[4];
#pragma unroll
        for (int i = 0; i < 4; ++i) {
            const int row = min(brow0 + r0 + 64 * i, 120000 - 1);
            a[i] = *(const uint4*)(Acat + (size_t)row * 320 + kt + q0);
        }
        const uint4 b0 = *(const uint4*)(vrelT + (size_t)r0 * 320 + kt + q0);
        __syncthreads();
#pragma unroll
        for (int i = 0; i < 4; ++i)
            *(uint4*)&As[(r0 + 64 * i) * 40 + q0] = a[i];
        *(uint4*)&Bs[r0 * 40 + q0] = b0;
        __syncthreads();
        short8 af[4], bf_[4];
#pragma unroll
        for (int m = 0; m < 4; ++m)
            af[m] = *(const short8*)&As[(wid * 64 + m * 16 + lrow) * 40 + kb * 8];
#pragma unroll
        for (int n = 0; n < 4; ++n)
            bf_[n] = *(const short8*)&Bs[(n * 16 + lrow) * 40 + kb * 8];
#pragma unroll
        for (int m = 0; m < 4; ++m)
#pragma unroll
            for (int n = 0; n < 4; ++n)
                acc[m][n] = __builtin_amdgcn_mfma_f32_16x16x32_bf16(af[m], bf_[n], acc[m][n], 0, 0, 0);
    }

#pragma unroll
    for (int m = 0; m < 4; ++m) {
        const int gr0 = brow0 + wid * 64 + m * 16 + kb * 4;
#pragma unroll
        for (int v = 0; v < 4; ++v) {
            const int grow = gr0 + v;
            if (grow < 120000) {
#pragma unroll
                for (int n = 0; n < 4; ++n) {
                    const int gcol = n * 16 + lrow;
                    const float x = acc[m][n][v];
                    const float g = 0.5f * x * (1.f + erff(x * 0.7071067811865475f));
                    aggVb[(size_t)grow * 64 + gcol] = f2bf(g);
                }
            }
        }
    }
}

// ---- MFMA out GEMM: out[30000,256] = sa*(aggVb @ Wob^T + out_b) + sb*hb (bf16 residual) ----
__global__ __launch_bounds__(256) void gemm_out_mfma(const unsigned short* __restrict__ A,
                                                     const unsigned short* __restrict__ Wob,
                                                     const float* __restrict__ bias,
                                                     float* __restrict__ C,
                                                     const unsigned short* __restrict__ hres,
                                                     const float* __restrict__ skip) {
    __shared__ unsigned short As[128 * 40];
    __shared__ unsigned short Bs[128 * 40];
    const int brow0 = blockIdx.x * 128;
    const int bcol0 = blockIdx.y * 128;
    const int t = threadIdx.x;
    const int wid = t >> 6, lane = t & 63;
    const int wr = wid >> 1, wc = wid & 1;
    const int lrow = lane & 15, kb = lane >> 4;
    const int r0 = t >> 2, q0 = t & 3;
    const int r1 = (t + 256) >> 2, q1 = t & 3;

    f32x4 acc[4][4];
#pragma unroll
    for (int m = 0; m < 4; ++m)
#pragma unroll
        for (int n = 0; n < 4; ++n) acc[m][n] = (f32x4)0.f;

    for (int kt = 0; kt < 256; kt += 32) {
        const int ar0 = min(brow0 + r0, N_NODES - 1);
        const int ar1 = min(brow0 + r1, N_NODES - 1);
        const uint4 a0 = *(const uint4*)(A + (size_t)ar0 * 256 + kt + q0 * 8);
        const uint4 a1 = *(const uint4*)(A + (size_t)ar1 * 256 + kt + q1 * 8);
        const uint4 b0 = *(const uint4*)(Wob + (size_t)(bcol0 + r0) * 256 + kt + q0 * 8);
        const uint4 b1 = *(const uint4*)(Wob + (size_t)(bcol0 + r1) * 256 + kt + q1 * 8);
        __syncthreads();
        *(uint4*)&As[r0 * 40 + q0 * 8] = a0;
        *(uint4*)&As[r1 * 40 + q1 * 8] = a1;
        *(uint4*)&Bs[r0 * 40 + q0 * 8] = b0;
        *(uint4*)&Bs[r1 * 40 + q1 * 8] = b1;
        __syncthreads();
        short8 af[4], bf_[4];
#pragma unroll
        for (int m = 0; m < 4; ++m)
            af[m] = *(const short8*)&As[(wr * 64 + m * 16 + lrow) * 40 + kb * 8];
#pragma unroll
        for (int n = 0; n < 4; ++n)
            bf_[n] = *(const short8*)&Bs[(wc * 64 + n * 16 + lrow) * 40 + kb * 8];
#pragma unroll
        for (int m = 0; m < 4; ++m)
#pragma unroll
            for (int n = 0; n < 4; ++n)
                acc[m][n] = __builtin_amdgcn_mfma_f32_16x16x32_bf16(af[m], bf_[n], acc[m][n], 0, 0, 0);
    }

    const float s = skip[0];
    const float sa = 1.f / (1.f + expf(-s));
    const float sb = 1.f - sa;
    float bias4[4];
#pragma unroll
    for (int n = 0; n < 4; ++n) bias4[n] = bias[bcol0 + wc * 64 + n * 16 + lrow];
#pragma unroll
    for (int m = 0; m < 4; ++m) {
        const int gr0 = brow0 + wr * 64 + m * 16 + kb * 4;
#pragma unroll
        for (int v = 0; v < 4; ++v) {
            const int grow = gr0 + v;
            if (grow < N_NODES) {
#pragma unroll
                for (int n = 0; n < 4; ++n) {
                    const int gcol = bcol0 + wc * 64 + n * 16 + lrow;
                    const float val = acc[m][n][v] + bias4[n];
                    C[(size_t)grow * 256 + gcol] = sa * val + sb * bf2f(hres[(size_t)grow * 256 + gcol]);
                }
            }
        }
    }
}

extern "C" void kernel_launch(void* const* d_in, const int* in_sizes, int n_in,
                              void* d_out, int out_size, void* d_ws, size_t ws_size,
                              hipStream_t stream) {
    const float* h      = (const float*)d_in[0];
    const int*   esrc   = (const int*)d_in[1];
    const int*   etgt   = (const int*)d_in[2];
    const float* kqv_w  = (const float*)d_in[3];
    const float* kqv_b  = (const float*)d_in[4];
    const float* out_w  = (const float*)d_in[5];
    const float* out_b  = (const float*)d_in[6];
    const float* k_rel  = (const float*)d_in[7];
    const float* v_rel  = (const float*)d_in[8];
    const float* skip   = (const float*)d_in[9];
    const float* p_rel  = (const float*)d_in[10];
    float* out = (float*)d_out;

    // workspace layout (float-sized slots):
    float* ws = (float*)d_ws;
    unsigned short* Ccat     = (unsigned short*)ws;                 // 26,880,000 slots [0 .. 26.88M)
    int*            deg      = (int*)(ws + 26880000);               //     30,000 -> 26,910,000
    int*            off      = (int*)(ws + 26910000);               //     30,000 -> 26,940,000
    int*            cursor   = (int*)(ws + 26940000);               //     30,000 -> 26,970,000
    int*            perm     = (int*)(ws + 26970000);               //    200,000 -> 27,170,000
    unsigned short* aggVb    = (unsigned short*)(ws + 27170000);    // 3,840,000 slots -> 31,010,000
    unsigned short* Acat     = (unsigned short*)(ws + 31010000);    // 19,200,000 slots -> 50,210,000
    // LATE-READ buffers (consumed AFTER Acat is written) -> past Acat's end:
    unsigned short* vrelT    = (unsigned short*)(ws + 50210000);    // 10,240 slots -> 50,220,240
    unsigned short* Wob      = (unsigned short*)(ws + 50220240);    // 32,768 slots -> 50,253,008
    unsigned short* hb       = (unsigned short*)(ws + 50253008);    // 3,840,000 slots -> 54,093,008
    //   (hb outside Acat's span: read late by gemm_out_mfma as bf16 residual)
    // EARLY-DEAD aliases inside Acat's span (read only BEFORE edge_fused writes Acat):
    unsigned short* Wcat     = (unsigned short*)(ws + 45370000);    // 229,376 slots -> ends 45,599,376
    float*          bias_cat = ws + 45600000;                       // 1,792 -> ends 45,601,792 (< 50.21M ok)
    // total footprint: 54,093,008 float slots = 216.4 MB (round 3 proved >= 219.9 MB available)

    hipLaunchKernelGGL(init_kernel, dim3(118), dim3(256), 0, stream, deg);
    hipLaunchKernelGGL(hist_kernel, dim3(782), dim3(256), 0, stream, etgt, deg);
    hipLaunchKernelGGL(scan_kernel, dim3(1), dim3(1024), 0, stream, deg, off, cursor);
    hipLaunchKernelGGL(scatter_kernel, dim3(782), dim3(256), 0, stream, etgt, esrc, cursor, perm);
    hipLaunchKernelGGL(prep_all, dim3(9628), dim3(256), 0, stream,
                       kqv_w, kqv_b, k_rel, p_rel, h, v_rel, out_w,
                       Wcat, bias_cat, hb, vrelT, Wob);
    hipLaunchKernelGGL(mfma_gemm, dim3(3290), dim3(256), 0, stream,
                       hb, Wcat, bias_cat, Ccat);
    hipLaunchKernelGGL(edge_fused, dim3(N_NODES / 4), dim3(256), 0, stream,
                       Ccat, off, perm, Acat);
    hipLaunchKernelGGL(gemm_cat_mfma, dim3(469), dim3(256), 0, stream,
                       Acat, vrelT, aggVb);
    hipLaunchKernelGGL(gemm_out_mfma, dim3(235, 2), dim3(256), 0, stream,
                       aggVb, Wob, out_b, out, hb, skip);
}

// Round 13
// 201.465 us; speedup vs baseline: 1.1672x; 1.1615x over previous
//
#include <hip/hip_runtime.h>
#include <hip/hip_bf16.h>
#include <math.h>

#define N_NODES 30000
#define NHEAD   4
#define HDIM    64
#define NTYPES  5
#define EPT     40000
#define TE      (NTYPES * EPT)
#define KDIM    256
#define NCAT    1792   // 1280 Ktil | 256 Q | 256 V
#define NBLK    118    // ceil(30000/256)

typedef __attribute__((ext_vector_type(8))) short short8;
typedef __attribute__((ext_vector_type(4))) float f32x4;

__device__ __forceinline__ unsigned short f2bf(float f) {
    __hip_bfloat16 h = __float2bfloat16(f);
    return *reinterpret_cast<unsigned short*>(&h);
}
__device__ __forceinline__ float bf2f(unsigned short u) {
    return __uint_as_float((unsigned)u << 16);
}

// async global->LDS, 16B per lane. LDS dest is wave-uniform base + lane*16 (linear).
__device__ __forceinline__ void gload16(const unsigned short* g, unsigned short* l) {
    __builtin_amdgcn_global_load_lds((const __attribute__((address_space(1))) void*)g,
                                     (__attribute__((address_space(3))) void*)l, 16, 0, 0);
}

// ---- init: zero deg ----
__global__ __launch_bounds__(256) void init_kernel(int* __restrict__ deg) {
    const int gid = blockIdx.x * blockDim.x + threadIdx.x;
    if (gid < N_NODES) deg[gid] = 0;
}

// ---- CSR build: histogram ----
__global__ __launch_bounds__(256) void hist_kernel(const int* __restrict__ etgt,
                                                   int* __restrict__ deg) {
    const int stride = gridDim.x * blockDim.x;
    for (int i = blockIdx.x * blockDim.x + threadIdx.x; i < TE; i += stride)
        atomicAdd(&deg[etgt[i]], 1);
}

// ---- hierarchical scan, stage 1: per-block sums (coalesced) ----
__global__ __launch_bounds__(256) void scan1_kernel(const int* __restrict__ deg,
                                                    int* __restrict__ bsum) {
    __shared__ int ws[4];
    const int t = threadIdx.x;
    const int gid = blockIdx.x * 256 + t;
    int d = (gid < N_NODES) ? deg[gid] : 0;
    d += __shfl_xor(d, 1);
    d += __shfl_xor(d, 2);
    d += __shfl_xor(d, 4);
    d += __shfl_xor(d, 8);
    d += __shfl_xor(d, 16);
    d += __shfl_xor(d, 32);
    if ((t & 63) == 0) ws[t >> 6] = d;
    __syncthreads();
    if (t == 0) bsum[blockIdx.x] = ws[0] + ws[1] + ws[2] + ws[3];
}

// ---- hierarchical scan, stage 2: exclusive scan of 118 block sums (1 block) ----
__global__ __launch_bounds__(128) void scan2_kernel(const int* __restrict__ bsum,
                                                    int* __restrict__ boff) {
    __shared__ int s[128];
    const int t = threadIdx.x;
    s[t] = (t < NBLK) ? bsum[t] : 0;
    __syncthreads();
    for (int d = 1; d < 128; d <<= 1) {
        const int v = (t >= d) ? s[t - d] : 0;
        __syncthreads();
        s[t] += v;
        __syncthreads();
    }
    if (t < NBLK) boff[t] = (t > 0) ? s[t - 1] : 0;
}

// ---- hierarchical scan, stage 3: in-block exclusive scan + block base (coalesced) ----
__global__ __launch_bounds__(256) void scan3_kernel(const int* __restrict__ deg,
                                                    const int* __restrict__ boff,
                                                    int* __restrict__ off,
                                                    int* __restrict__ cursor) {
    __shared__ int s[256];
    const int t = threadIdx.x;
    const int gid = blockIdx.x * 256 + t;
    const int d = (gid < N_NODES) ? deg[gid] : 0;
    s[t] = d;
    __syncthreads();
    for (int dd = 1; dd < 256; dd <<= 1) {
        const int v = (t >= dd) ? s[t - dd] : 0;
        __syncthreads();
        s[t] += v;
        __syncthreads();
    }
    if (gid < N_NODES) {
        const int excl = s[t] - d + boff[blockIdx.x];
        off[gid] = excl;
        cursor[gid] = excl;
    }
}

// ---- CSR build: scatter PACKED (src | t<<16) into per-target buckets ----
__global__ __launch_bounds__(256) void scatter_kernel(const int* __restrict__ etgt,
                                                      const int* __restrict__ esrc,
                                                      int* __restrict__ cursor,
                                                      int* __restrict__ perm) {
    const int stride = gridDim.x * blockDim.x;
    for (int e = blockIdx.x * blockDim.x + threadIdx.x; e < TE; e += stride) {
        const int pos = atomicAdd(&cursor[etgt[e]], 1);
        perm[pos] = esrc[e] | ((e / EPT) << 16);
    }
}

// ---- merged prep: [0,1792) weight_prep | [1792,9292) h2bf | [9292,9372) vrelT | [9372,9628) owb ----
__global__ __launch_bounds__(256) void prep_all(const float* __restrict__ kqv_w,
                                                const float* __restrict__ kqv_b,
                                                const float* __restrict__ k_rel,
                                                const float* __restrict__ p_rel,
                                                const float* __restrict__ h,
                                                const float* __restrict__ v_rel,
                                                const float* __restrict__ out_w,
                                                unsigned short* __restrict__ Wcat,
                                                float* __restrict__ bias_cat,
                                                unsigned short* __restrict__ hb,
                                                unsigned short* __restrict__ vrelT,
                                                unsigned short* __restrict__ Wob) {
    const int bid = blockIdx.x;
    const int tid = threadIdx.x;
    if (bid < 1792) {
        const int r = bid, f = tid;
        if (r < 1280) {
            const int t = r >> 8, hh = (r >> 6) & 3, d = r & 63;
            const float sc = 0.125f * p_rel[t * NHEAD + hh];
            float acc = 0.f;
#pragma unroll
            for (int fp = 0; fp < 64; ++fp)
                acc = fmaf(kqv_w[(size_t)(hh * 64 + fp) * 256 + f], k_rel[t * 4096 + fp * 64 + d], acc);
            Wcat[(size_t)r * 256 + f] = f2bf(acc * sc);
            if (f == 0) {
                float b = 0.f;
#pragma unroll
                for (int fp = 0; fp < 64; ++fp)
                    b = fmaf(kqv_b[hh * 64 + fp], k_rel[t * 4096 + fp * 64 + d], b);
                bias_cat[r] = b * sc;
            }
        } else {
            const int src_row = r - 1024;  // 1280->256 (Q), 1536->512 (V)
            Wcat[(size_t)r * 256 + f] = f2bf(kqv_w[(size_t)src_row * 256 + f]);
            if (f == 0) bias_cat[r] = kqv_b[src_row];
        }
    } else if (bid < 9292) {
        const int i = (bid - 1792) * 256 + tid;   // exactly 1,920,000 float4s
        const float4 v = ((const float4*)h)[i];
        ushort4 u;
        u.x = f2bf(v.x); u.y = f2bf(v.y); u.z = f2bf(v.z); u.w = f2bf(v.w);
        ((ushort4*)hb)[i] = u;
    } else if (bid < 9372) {
        const int idx = (bid - 9292) * 256 + tid;
        if (idx < 64 * 320) {
            const int f = idx / 320, k = idx - f * 320;
            vrelT[f * 320 + k] = f2bf(v_rel[(k >> 6) * 4096 + (k & 63) * 64 + f]);
        }
    } else {
        const int i = (bid - 9372) * 256 + tid;   // exactly 65,536
        Wob[i] = f2bf(out_w[i]);
    }
}

// ---- MFMA GEMM: Ccat[30000,1792](bf16) = hb[30000,256] @ Wcat^T + bias_cat ----
__global__ __launch_bounds__(256) void mfma_gemm(const unsigned short* __restrict__ hb,
                                                 const unsigned short* __restrict__ Wcat,
                                                 const float* __restrict__ bias_cat,
                                                 unsigned short* __restrict__ Ccat) {
    __shared__ unsigned short As[2][128 * 32];
    __shared__ unsigned short Bs[2][128 * 32];
    // bijective chunked swizzle over 3290 = 235*14 blocks, 8 XCDs (m204)
    const int orig = blockIdx.x;
    const int xcd = orig & 7, pos = orig >> 3;
    const int q = 3290 / 8, r = 3290 % 8;  // 411, 2
    const int wgid = (xcd < r ? xcd * (q + 1) : r * (q + 1) + (xcd - r) * q) + pos;
    const int brow0 = (wgid / 14) * 128;
    const int bcol0 = (wgid % 14) * 128;

    const int t = threadIdx.x;
    const int wid = t >> 6, lane = t & 63;
    const int wr = wid >> 1, wc = wid & 1;
    const int lrow = lane & 15, kb = lane >> 4;
    const int srow = lane >> 2;
    const int schunk = ((lane & 3) ^ ((lane >> 3) & 3)) * 8;   // staged (swizzled) chunk
    const int rchunk = (kb ^ ((lrow >> 1) & 3)) * 8;           // swizzled read chunk

    const int arow0 = min(brow0 + wid * 16 + srow, N_NODES - 1);
    const int arow1 = min(brow0 + 64 + wid * 16 + srow, N_NODES - 1);
    const int brw0 = bcol0 + wid * 16 + srow;        // always < 1792
    const int brw1 = bcol0 + 64 + wid * 16 + srow;

    auto stage = [&](int buf, int kt) {
        gload16(hb + (size_t)arow0 * KDIM + kt + schunk, &As[buf][wid * 512]);
        gload16(hb + (size_t)arow1 * KDIM + kt + schunk, &As[buf][2048 + wid * 512]);
        gload16(Wcat + (size_t)brw0 * KDIM + kt + schunk, &Bs[buf][wid * 512]);
        gload16(Wcat + (size_t)brw1 * KDIM + kt + schunk, &Bs[buf][2048 + wid * 512]);
    };

    f32x4 acc[4][4];
#pragma unroll
    for (int m = 0; m < 4; ++m)
#pragma unroll
        for (int n = 0; n < 4; ++n) acc[m][n] = (f32x4)0.f;

    stage(0, 0);
    __syncthreads();
    int cur = 0;
    for (int kt = 0; kt < KDIM; kt += 32) {
        if (kt + 32 < KDIM) stage(cur ^ 1, kt + 32);
        short8 af[4], bfr[4];
#pragma unroll
        for (int m = 0; m < 4; ++m)
            af[m] = *(const short8*)&As[cur][(wr * 64 + m * 16 + lrow) * 32 + rchunk];
#pragma unroll
        for (int n = 0; n < 4; ++n)
            bfr[n] = *(const short8*)&Bs[cur][(wc * 64 + n * 16 + lrow) * 32 + rchunk];
#pragma unroll
        for (int m = 0; m < 4; ++m)
#pragma unroll
            for (int n = 0; n < 4; ++n)
                acc[m][n] = __builtin_amdgcn_mfma_f32_16x16x32_bf16(af[m], bfr[n], acc[m][n], 0, 0, 0);
        __syncthreads();
        cur ^= 1;
    }

    // ---- LDS-transpose epilogue: dwordx4 C-stores ----
    unsigned short* Ts = &As[0][0];
    float bias4[4];
#pragma unroll
    for (int n = 0; n < 4; ++n) bias4[n] = bias_cat[bcol0 + wc * 64 + n * 16 + lrow];
    const int lrw = wr * 16 + kb * 4;
    const int lcw = wc * 64 + lrow;
#pragma unroll
    for (int m = 0; m < 4; ++m) {
        __syncthreads();
#pragma unroll
        for (int n = 0; n < 4; ++n)
#pragma unroll
            for (int v = 0; v < 4; ++v)
                Ts[(lrw + v) * 132 + lcw + n * 16] = f2bf(acc[m][n][v] + bias4[n]);
        __syncthreads();
#pragma unroll
        for (int rd = 0; rd < 2; ++rd) {
            const int lr = (t >> 4) + rd * 16;          // 0..31
            const int c0 = (t & 15) * 8;                // 0..120 step 8
            const int grow = brow0 + (lr >> 4) * 64 + m * 16 + (lr & 15);
            if (grow < N_NODES) {
                const uint2 lo = *(const uint2*)&Ts[lr * 132 + c0];
                const uint2 hi = *(const uint2*)&Ts[lr * 132 + c0 + 4];
                const uint4 o = make_uint4(lo.x, lo.y, hi.x, hi.y);
                *(uint4*)&Ccat[(size_t)grow * NCAT + bcol0 + c0] = o;
            }
        }
    }
}

// ---- fused edge pass: one wave per target, packed-src CSR walk (round-10 text). ----
__global__ __launch_bounds__(256) void edge_fused(const unsigned short* __restrict__ Ccat,
                                                  const int* __restrict__ off,
                                                  const int* __restrict__ perm,
                                                  unsigned short* __restrict__ Acat) {
    const int wid = threadIdx.x >> 6, lane = threadIdx.x & 63;
    const int tgt = (blockIdx.x << 2) + wid;
    const int h = lane >> 4, f0 = (lane & 15) << 2;
    const int off0 = off[tgt];
    const int off1 = (tgt == N_NODES - 1) ? TE : off[tgt + 1];
    const ushort4 qu = *(const ushort4*)(Ccat + (size_t)tgt * NCAT + 1280 + (h << 6) + f0);
    const float qx = bf2f(qu.x), qy = bf2f(qu.y), qz = bf2f(qu.z), qw = bf2f(qu.w);
    const int voff = 1536 + (h << 6) + f0;
    float es = 0.f;
    float4 a0 = make_float4(0, 0, 0, 0), a1 = a0, a2 = a0, a3 = a0, a4 = a0;
    int i = off0;
    while (i < off1) {
        const bool two = (i + 1 < off1);
        const int pk0 = perm[i];
        const int pk1 = two ? perm[i + 1] : pk0;
        const int s0 = pk0 & 0xFFFF, t0 = pk0 >> 16;
        const int s1 = pk1 & 0xFFFF, t1 = pk1 >> 16;
        const size_t rb0 = (size_t)s0 * NCAT, rb1 = (size_t)s1 * NCAT;
        // issue all 4 gathers before any compute (2x memory-level parallelism)
        const ushort4 ku0 = *(const ushort4*)(Ccat + rb0 + ((t0 * 4 + h) << 6) + f0);
        const ushort4 vu0 = *(const ushort4*)(Ccat + rb0 + voff);
        const ushort4 ku1 = *(const ushort4*)(Ccat + rb1 + ((t1 * 4 + h) << 6) + f0);
        const ushort4 vu1 = *(const ushort4*)(Ccat + rb1 + voff);
        float p0 = qx * bf2f(ku0.x) + qy * bf2f(ku0.y) + qz * bf2f(ku0.z) + qw * bf2f(ku0.w);
        float p1 = qx * bf2f(ku1.x) + qy * bf2f(ku1.y) + qz * bf2f(ku1.z) + qw * bf2f(ku1.w);
        p0 += __shfl_xor(p0, 1); p1 += __shfl_xor(p1, 1);
        p0 += __shfl_xor(p0, 2); p1 += __shfl_xor(p1, 2);
        p0 += __shfl_xor(p0, 4); p1 += __shfl_xor(p1, 4);
        p0 += __shfl_xor(p0, 8); p1 += __shfl_xor(p1, 8);
        {
            const float ex = __expf(p0);
            es += ex;
            const float mx = ex * bf2f(vu0.x), my = ex * bf2f(vu0.y);
            const float mz = ex * bf2f(vu0.z), mw = ex * bf2f(vu0.w);
            if (t0 == 0)      { a0.x += mx; a0.y += my; a0.z += mz; a0.w += mw; }
            else if (t0 == 1) { a1.x += mx; a1.y += my; a1.z += mz; a1.w += mw; }
            else if (t0 == 2) { a2.x += mx; a2.y += my; a2.z += mz; a2.w += mw; }
            else if (t0 == 3) { a3.x += mx; a3.y += my; a3.z += mz; a3.w += mw; }
            else              { a4.x += mx; a4.y += my; a4.z += mz; a4.w += mw; }
        }
        if (two) {
            const float ex = __expf(p1);
            es += ex;
            const float mx = ex * bf2f(vu1.x), my = ex * bf2f(vu1.y);
            const float mz = ex * bf2f(vu1.z), mw = ex * bf2f(vu1.w);
            if (t1 == 0)      { a0.x += mx; a0.y += my; a0.z += mz; a0.w += mw; }
            else if (t1 == 1) { a1.x += mx; a1.y += my; a1.z += mz; a1.w += mw; }
            else if (t1 == 2) { a2.x += mx; a2.y += my; a2.z += mz; a2.w += mw; }
            else if (t1 == 3) { a3.x += mx; a3.y += my; a3.z += mz; a3.w += mw; }
            else              { a4.x += mx; a4.y += my; a4.z += mz; a4.w += mw; }
        }
        i += two ? 2 : 1;
    }
    const float inv = 1.f / (es + 1e-16f);
    const size_t rr = (size_t)tgt * NHEAD + h;
    unsigned short* base = Acat + rr * (NTYPES * HDIM) + f0;
    ushort4 u;
    u.x = f2bf(a0.x * inv); u.y = f2bf(a0.y * inv); u.z = f2bf(a0.z * inv); u.w = f2bf(a0.w * inv);
    *(ushort4*)(base + 0 * HDIM) = u;
    u.x = f2bf(a1.x * inv); u.y = f2bf(a1.y * inv); u.z = f2bf(a1.z * inv); u.w = f2bf(a1.w * inv);
    *(ushort4*)(base + 1 * HDIM) = u;
    u.x = f2bf(a2.x * inv); u.y = f2bf(a2.y * inv); u.z = f2bf(a2.z * inv); u.w = f2bf(a2.w * inv);
    *(ushort4*)(base + 2 * HDIM) = u;
    u.x = f2bf(a3.x * inv); u.y = f2bf(a3.y * inv); u.z = f2bf(a3.z * inv); u.w = f2bf(a3.w * inv);
    *(ushort4*)(base + 3 * HDIM) = u;
    u.x = f2bf(a4.x * inv); u.y = f2bf(a4.y * inv); u.z = f2bf(a4.z * inv); u.w = f2bf(a4.w * inv);
    *(ushort4*)(base + 4 * HDIM) = u;
}

// ---- MFMA epilogue GEMM: aggVb[120000,64](bf16) = gelu(Acat[120000,320] @ vrelT^T) ----
__global__ __launch_bounds__(256) void gemm_cat_mfma(const unsigned short* __restrict__ Acat,
                                                     const unsigned short* __restrict__ vrelT,
                                                     unsigned short* __restrict__ aggVb) {
    __shared__ unsigned short As[256 * 40];
    __shared__ unsigned short Bs[64 * 40];
    const int brow0 = blockIdx.x * 256;
    const int t = threadIdx.x;
    const int wid = t >> 6, lane = t & 63;
    const int lrow = lane & 15, kb = lane >> 4;
    const int r0 = t >> 2, q0 = (t & 3) * 8;

    f32x4 acc[4][4];
#pragma unroll
    for (int m = 0; m < 4; ++m)
#pragma unroll
        for (int n = 0; n < 4; ++n) acc[m][n] = (f32x4)0.f;

    for (int kt = 0; kt < 320; kt += 32) {
        uint4 a[4];
#pragma unroll
        for (int i = 0; i < 4; ++i) {
            const int row = min(brow0 + r0 + 64 * i, 120000 - 1);
            a[i] = *(const uint4*)(Acat + (size_t)row * 320 + kt + q0);
        }
        const uint4 b0 = *(const uint4*)(vrelT + (size_t)r0 * 320 + kt + q0);
        __syncthreads();
#pragma unroll
        for (int i = 0; i < 4; ++i)
            *(uint4*)&As[(r0 + 64 * i) * 40 + q0] = a[i];
        *(uint4*)&Bs[r0 * 40 + q0] = b0;
        __syncthreads();
        short8 af[4], bf_[4];
#pragma unroll
        for (int m = 0; m < 4; ++m)
            af[m] = *(const short8*)&As[(wid * 64 + m * 16 + lrow) * 40 + kb * 8];
#pragma unroll
        for (int n = 0; n < 4; ++n)
            bf_[n] = *(const short8*)&Bs[(n * 16 + lrow) * 40 + kb * 8];
#pragma unroll
        for (int m = 0; m < 4; ++m)
#pragma unroll
            for (int n = 0; n < 4; ++n)
                acc[m][n] = __builtin_amdgcn_mfma_f32_16x16x32_bf16(af[m], bf_[n], acc[m][n], 0, 0, 0);
    }

#pragma unroll
    for (int m = 0; m < 4; ++m) {
        const int gr0 = brow0 + wid * 64 + m * 16 + kb * 4;
#pragma unroll
        for (int v = 0; v < 4; ++v) {
            const int grow = gr0 + v;
            if (grow < 120000) {
#pragma unroll
                for (int n = 0; n < 4; ++n) {
                    const int gcol = n * 16 + lrow;
                    const float x = acc[m][n][v];
                    const float g = 0.5f * x * (1.f + erff(x * 0.7071067811865475f));
                    aggVb[(size_t)grow * 64 + gcol] = f2bf(g);
                }
            }
        }
    }
}

// ---- MFMA out GEMM: out[30000,256] = sa*(aggVb @ Wob^T + out_b) + sb*hb (bf16 residual) ----
__global__ __launch_bounds__(256) void gemm_out_mfma(const unsigned short* __restrict__ A,
                                                     const unsigned short* __restrict__ Wob,
                                                     const float* __restrict__ bias,
                                                     float* __restrict__ C,
                                                     const unsigned short* __restrict__ hres,
                                                     const float* __restrict__ skip) {
    __shared__ unsigned short As[128 * 40];
    __shared__ unsigned short Bs[128 * 40];
    const int brow0 = blockIdx.x * 128;
    const int bcol0 = blockIdx.y * 128;
    const int t = threadIdx.x;
    const int wid = t >> 6, lane = t & 63;
    const int wr = wid >> 1, wc = wid & 1;
    const int lrow = lane & 15, kb = lane >> 4;
    const int r0 = t >> 2, q0 = t & 3;
    const int r1 = (t + 256) >> 2, q1 = t & 3;

    f32x4 acc[4][4];
#pragma unroll
    for (int m = 0; m < 4; ++m)
#pragma unroll
        for (int n = 0; n < 4; ++n) acc[m][n] = (f32x4)0.f;

    for (int kt = 0; kt < 256; kt += 32) {
        const int ar0 = min(brow0 + r0, N_NODES - 1);
        const int ar1 = min(brow0 + r1, N_NODES - 1);
        const uint4 a0 = *(const uint4*)(A + (size_t)ar0 * 256 + kt + q0 * 8);
        const uint4 a1 = *(const uint4*)(A + (size_t)ar1 * 256 + kt + q1 * 8);
        const uint4 b0 = *(const uint4*)(Wob + (size_t)(bcol0 + r0) * 256 + kt + q0 * 8);
        const uint4 b1 = *(const uint4*)(Wob + (size_t)(bcol0 + r1) * 256 + kt + q1 * 8);
        __syncthreads();
        *(uint4*)&As[r0 * 40 + q0 * 8] = a0;
        *(uint4*)&As[r1 * 40 + q1 * 8] = a1;
        *(uint4*)&Bs[r0 * 40 + q0 * 8] = b0;
        *(uint4*)&Bs[r1 * 40 + q1 * 8] = b1;
        __syncthreads();
        short8 af[4], bf_[4];
#pragma unroll
        for (int m = 0; m < 4; ++m)
            af[m] = *(const short8*)&As[(wr * 64 + m * 16 + lrow) * 40 + kb * 8];
#pragma unroll
        for (int n = 0; n < 4; ++n)
            bf_[n] = *(const short8*)&Bs[(wc * 64 + n * 16 + lrow) * 40 + kb * 8];
#pragma unroll
        for (int m = 0; m < 4; ++m)
#pragma unroll
            for (int n = 0; n < 4; ++n)
                acc[m][n] = __builtin_amdgcn_mfma_f32_16x16x32_bf16(af[m], bf_[n], acc[m][n], 0, 0, 0);
    }

    const float s = skip[0];
    const float sa = 1.f / (1.f + expf(-s));
    const float sb = 1.f - sa;
    float bias4[4];
#pragma unroll
    for (int n = 0; n < 4; ++n) bias4[n] = bias[bcol0 + wc * 64 + n * 16 + lrow];
#pragma unroll
    for (int m = 0; m < 4; ++m) {
        const int gr0 = brow0 + wr * 64 + m * 16 + kb * 4;
#pragma unroll
        for (int v = 0; v < 4; ++v) {
            const int grow = gr0 + v;
            if (grow < N_NODES) {
#pragma unroll
                for (int n = 0; n < 4; ++n) {
                    const int gcol = bcol0 + wc * 64 + n * 16 + lrow;
                    const float val = acc[m][n][v] + bias4[n];
                    C[(size_t)grow * 256 + gcol] = sa * val + sb * bf2f(hres[(size_t)grow * 256 + gcol]);
                }
            }
        }
    }
}

extern "C" void kernel_launch(void* const* d_in, const int* in_sizes, int n_in,
                              void* d_out, int out_size, void* d_ws, size_t ws_size,
                              hipStream_t stream) {
    const float* h      = (const float*)d_in[0];
    const int*   esrc   = (const int*)d_in[1];
    const int*   etgt   = (const int*)d_in[2];
    const float* kqv_w  = (const float*)d_in[3];
    const float* kqv_b  = (const float*)d_in[4];
    const float* out_w  = (const float*)d_in[5];
    const float* out_b  = (const float*)d_in[6];
    const float* k_rel  = (const float*)d_in[7];
    const float* v_rel  = (const float*)d_in[8];
    const float* skip   = (const float*)d_in[9];
    const float* p_rel  = (const float*)d_in[10];
    float* out = (float*)d_out;

    // workspace layout (float-sized slots):
    float* ws = (float*)d_ws;
    unsigned short* Ccat     = (unsigned short*)ws;                 // 26,880,000 slots [0 .. 26.88M)
    int*            deg      = (int*)(ws + 26880000);               //     30,000 -> 26,910,000
    int*            off      = (int*)(ws + 26910000);               //     30,000 -> 26,940,000
    int*            cursor   = (int*)(ws + 26940000);               //     30,000 -> 26,970,000
    int*            perm     = (int*)(ws + 26970000);               //    200,000 -> 27,170,000
    unsigned short* aggVb    = (unsigned short*)(ws + 27170000);    // 3,840,000 slots -> 31,010,000
    unsigned short* Acat     = (unsigned short*)(ws + 31010000);    // 19,200,000 slots -> 50,210,000
    // LATE-READ buffers (consumed AFTER Acat is written) -> past Acat's end:
    unsigned short* vrelT    = (unsigned short*)(ws + 50210000);    // 10,240 slots -> 50,220,240
    unsigned short* Wob      = (unsigned short*)(ws + 50220240);    // 32,768 slots -> 50,253,008
    unsigned short* hb       = (unsigned short*)(ws + 50253008);    // 3,840,000 slots -> 54,093,008
    int*            bsum     = (int*)(ws + 54093008);               //        118 -> 54,093,126
    int*            boff     = (int*)(ws + 54093126);               //        118 -> 54,093,244
    // EARLY-DEAD aliases inside Acat's span (read only BEFORE edge_fused writes Acat):
    unsigned short* Wcat     = (unsigned short*)(ws + 45370000);    // 229,376 slots -> ends 45,599,376
    float*          bias_cat = ws + 45600000;                       // 1,792 -> ends 45,601,792 (< 50.21M ok)
    // total footprint: 54,093,244 float slots = 216.4 MB (round 3 proved >= 219.9 MB available)

    hipLaunchKernelGGL(init_kernel, dim3(NBLK), dim3(256), 0, stream, deg);
    hipLaunchKernelGGL(hist_kernel, dim3(782), dim3(256), 0, stream, etgt, deg);
    hipLaunchKernelGGL(scan1_kernel, dim3(NBLK), dim3(256), 0, stream, deg, bsum);
    hipLaunchKernelGGL(scan2_kernel, dim3(1), dim3(128), 0, stream, bsum, boff);
    hipLaunchKernelGGL(scan3_kernel, dim3(NBLK), dim3(256), 0, stream, deg, boff, off, cursor);
    hipLaunchKernelGGL(scatter_kernel, dim3(782), dim3(256), 0, stream, etgt, esrc, cursor, perm);
    hipLaunchKernelGGL(prep_all, dim3(9628), dim3(256), 0, stream,
                       kqv_w, kqv_b, k_rel, p_rel, h, v_rel, out_w,
                       Wcat, bias_cat, hb, vrelT, Wob);
    hipLaunchKernelGGL(mfma_gemm, dim3(3290), dim3(256), 0, stream,
                       hb, Wcat, bias_cat, Ccat);
    hipLaunchKernelGGL(edge_fused, dim3(N_NODES / 4), dim3(256), 0, stream,
                       Ccat, off, perm, Acat);
    hipLaunchKernelGGL(gemm_cat_mfma, dim3(469), dim3(256), 0, stream,
                       Acat, vrelT, aggVb);
    hipLaunchKernelGGL(gemm_out_mfma, dim3(235, 2), dim3(256), 0, stream,
                       aggVb, Wob, out_b, out, hb, skip);
}

// Round 14
// 198.550 us; speedup vs baseline: 1.1843x; 1.0147x over previous
//
#include <hip/hip_runtime.h>
#include <hip/hip_bf16.h>
#include <math.h>

#define N_NODES 30000
#define NHEAD   4
#define HDIM    64
#define NTYPES  5
#define EPT     40000
#define TE      (NTYPES * EPT)
#define KDIM    256
#define NCAT    1792   // 1280 Ktil | 256 Q | 256 V
#define NBLK    118    // ceil(30000/256)

typedef __attribute__((ext_vector_type(8))) short short8;
typedef __attribute__((ext_vector_type(4))) float f32x4;

__device__ __forceinline__ unsigned short f2bf(float f) {
    __hip_bfloat16 h = __float2bfloat16(f);
    return *reinterpret_cast<unsigned short*>(&h);
}
__device__ __forceinline__ float bf2f(unsigned short u) {
    return __uint_as_float((unsigned)u << 16);
}

// async global->LDS, 16B per lane. LDS dest is wave-uniform base + lane*16 (linear).
__device__ __forceinline__ void gload16(const unsigned short* g, unsigned short* l) {
    __builtin_amdgcn_global_load_lds((const __attribute__((address_space(1))) void*)g,
                                     (__attribute__((address_space(3))) void*)l, 16, 0, 0);
}

// ---- init: zero deg ----
__global__ __launch_bounds__(256) void init_kernel(int* __restrict__ deg) {
    const int gid = blockIdx.x * blockDim.x + threadIdx.x;
    if (gid < N_NODES) deg[gid] = 0;
}

// ---- CSR build: histogram ----
__global__ __launch_bounds__(256) void hist_kernel(const int* __restrict__ etgt,
                                                   int* __restrict__ deg) {
    const int stride = gridDim.x * blockDim.x;
    for (int i = blockIdx.x * blockDim.x + threadIdx.x; i < TE; i += stride)
        atomicAdd(&deg[etgt[i]], 1);
}

// ---- hierarchical scan, stage 1: per-block sums (coalesced) ----
__global__ __launch_bounds__(256) void scan1_kernel(const int* __restrict__ deg,
                                                    int* __restrict__ bsum) {
    __shared__ int ws[4];
    const int t = threadIdx.x;
    const int gid = blockIdx.x * 256 + t;
    int d = (gid < N_NODES) ? deg[gid] : 0;
    d += __shfl_xor(d, 1);
    d += __shfl_xor(d, 2);
    d += __shfl_xor(d, 4);
    d += __shfl_xor(d, 8);
    d += __shfl_xor(d, 16);
    d += __shfl_xor(d, 32);
    if ((t & 63) == 0) ws[t >> 6] = d;
    __syncthreads();
    if (t == 0) bsum[blockIdx.x] = ws[0] + ws[1] + ws[2] + ws[3];
}

// ---- hierarchical scan, stage 2: exclusive scan of 118 block sums (1 block) ----
__global__ __launch_bounds__(128) void scan2_kernel(const int* __restrict__ bsum,
                                                    int* __restrict__ boff) {
    __shared__ int s[128];
    const int t = threadIdx.x;
    s[t] = (t < NBLK) ? bsum[t] : 0;
    __syncthreads();
    for (int d = 1; d < 128; d <<= 1) {
        const int v = (t >= d) ? s[t - d] : 0;
        __syncthreads();
        s[t] += v;
        __syncthreads();
    }
    if (t < NBLK) boff[t] = (t > 0) ? s[t - 1] : 0;
}

// ---- hierarchical scan, stage 3: in-block exclusive scan + block base (coalesced) ----
__global__ __launch_bounds__(256) void scan3_kernel(const int* __restrict__ deg,
                                                    const int* __restrict__ boff,
                                                    int* __restrict__ off,
                                                    int* __restrict__ cursor) {
    __shared__ int s[256];
    const int t = threadIdx.x;
    const int gid = blockIdx.x * 256 + t;
    const int d = (gid < N_NODES) ? deg[gid] : 0;
    s[t] = d;
    __syncthreads();
    for (int dd = 1; dd < 256; dd <<= 1) {
        const int v = (t >= dd) ? s[t - dd] : 0;
        __syncthreads();
        s[t] += v;
        __syncthreads();
    }
    if (gid < N_NODES) {
        const int excl = s[t] - d + boff[blockIdx.x];
        off[gid] = excl;
        cursor[gid] = excl;
    }
}

// ---- CSR build: scatter PACKED (src | t<<16) into per-target buckets ----
__global__ __launch_bounds__(256) void scatter_kernel(const int* __restrict__ etgt,
                                                      const int* __restrict__ esrc,
                                                      int* __restrict__ cursor,
                                                      int* __restrict__ perm) {
    const int stride = gridDim.x * blockDim.x;
    for (int e = blockIdx.x * blockDim.x + threadIdx.x; e < TE; e += stride) {
        const int pos = atomicAdd(&cursor[etgt[e]], 1);
        perm[pos] = esrc[e] | ((e / EPT) << 16);
    }
}

// ---- merged prep: [0,1792) weight_prep | [1792,9292) h2bf | [9292,9372) vrelT | [9372,9628) owb ----
__global__ __launch_bounds__(256) void prep_all(const float* __restrict__ kqv_w,
                                                const float* __restrict__ kqv_b,
                                                const float* __restrict__ k_rel,
                                                const float* __restrict__ p_rel,
                                                const float* __restrict__ h,
                                                const float* __restrict__ v_rel,
                                                const float* __restrict__ out_w,
                                                unsigned short* __restrict__ Wcat,
                                                float* __restrict__ bias_cat,
                                                unsigned short* __restrict__ hb,
                                                unsigned short* __restrict__ vrelT,
                                                unsigned short* __restrict__ Wob) {
    const int bid = blockIdx.x;
    const int tid = threadIdx.x;
    if (bid < 1792) {
        const int r = bid, f = tid;
        if (r < 1280) {
            const int t = r >> 8, hh = (r >> 6) & 3, d = r & 63;
            const float sc = 0.125f * p_rel[t * NHEAD + hh];
            float acc = 0.f;
#pragma unroll
            for (int fp = 0; fp < 64; ++fp)
                acc = fmaf(kqv_w[(size_t)(hh * 64 + fp) * 256 + f], k_rel[t * 4096 + fp * 64 + d], acc);
            Wcat[(size_t)r * 256 + f] = f2bf(acc * sc);
            if (f == 0) {
                float b = 0.f;
#pragma unroll
                for (int fp = 0; fp < 64; ++fp)
                    b = fmaf(kqv_b[hh * 64 + fp], k_rel[t * 4096 + fp * 64 + d], b);
                bias_cat[r] = b * sc;
            }
        } else {
            const int src_row = r - 1024;  // 1280->256 (Q), 1536->512 (V)
            Wcat[(size_t)r * 256 + f] = f2bf(kqv_w[(size_t)src_row * 256 + f]);
            if (f == 0) bias_cat[r] = kqv_b[src_row];
        }
    } else if (bid < 9292) {
        const int i = (bid - 1792) * 256 + tid;   // exactly 1,920,000 float4s
        const float4 v = ((const float4*)h)[i];
        ushort4 u;
        u.x = f2bf(v.x); u.y = f2bf(v.y); u.z = f2bf(v.z); u.w = f2bf(v.w);
        ((ushort4*)hb)[i] = u;
    } else if (bid < 9372) {
        const int idx = (bid - 9292) * 256 + tid;
        if (idx < 64 * 320) {
            const int f = idx / 320, k = idx - f * 320;
            vrelT[f * 320 + k] = f2bf(v_rel[(k >> 6) * 4096 + (k & 63) * 64 + f]);
        }
    } else {
        const int i = (bid - 9372) * 256 + tid;   // exactly 65,536
        Wob[i] = f2bf(out_w[i]);
    }
}

// ---- MFMA GEMM: Ccat[30000,1792](bf16) = hb[30000,256] @ Wcat^T + bias_cat ----
__global__ __launch_bounds__(256) void mfma_gemm(const unsigned short* __restrict__ hb,
                                                 const unsigned short* __restrict__ Wcat,
                                                 const float* __restrict__ bias_cat,
                                                 unsigned short* __restrict__ Ccat) {
    __shared__ unsigned short As[2][128 * 32];
    __shared__ unsigned short Bs[2][128 * 32];
    // bijective chunked swizzle over 3290 = 235*14 blocks, 8 XCDs (m204)
    const int orig = blockIdx.x;
    const int xcd = orig & 7, pos = orig >> 3;
    const int q = 3290 / 8, r = 3290 % 8;  // 411, 2
    const int wgid = (xcd < r ? xcd * (q + 1) : r * (q + 1) + (xcd - r) * q) + pos;
    const int brow0 = (wgid / 14) * 128;
    const int bcol0 = (wgid % 14) * 128;

    const int t = threadIdx.x;
    const int wid = t >> 6, lane = t & 63;
    const int wr = wid >> 1, wc = wid & 1;
    const int lrow = lane & 15, kb = lane >> 4;
    const int srow = lane >> 2;
    const int schunk = ((lane & 3) ^ ((lane >> 3) & 3)) * 8;   // staged (swizzled) chunk
    const int rchunk = (kb ^ ((lrow >> 1) & 3)) * 8;           // swizzled read chunk

    const int arow0 = min(brow0 + wid * 16 + srow, N_NODES - 1);
    const int arow1 = min(brow0 + 64 + wid * 16 + srow, N_NODES - 1);
    const int brw0 = bcol0 + wid * 16 + srow;        // always < 1792
    const int brw1 = bcol0 + 64 + wid * 16 + srow;

    auto stage = [&](int buf, int kt) {
        gload16(hb + (size_t)arow0 * KDIM + kt + schunk, &As[buf][wid * 512]);
        gload16(hb + (size_t)arow1 * KDIM + kt + schunk, &As[buf][2048 + wid * 512]);
        gload16(Wcat + (size_t)brw0 * KDIM + kt + schunk, &Bs[buf][wid * 512]);
        gload16(Wcat + (size_t)brw1 * KDIM + kt + schunk, &Bs[buf][2048 + wid * 512]);
    };

    f32x4 acc[4][4];
#pragma unroll
    for (int m = 0; m < 4; ++m)
#pragma unroll
        for (int n = 0; n < 4; ++n) acc[m][n] = (f32x4)0.f;

    stage(0, 0);
    __syncthreads();
    int cur = 0;
    for (int kt = 0; kt < KDIM; kt += 32) {
        if (kt + 32 < KDIM) stage(cur ^ 1, kt + 32);
        short8 af[4], bfr[4];
#pragma unroll
        for (int m = 0; m < 4; ++m)
            af[m] = *(const short8*)&As[cur][(wr * 64 + m * 16 + lrow) * 32 + rchunk];
#pragma unroll
        for (int n = 0; n < 4; ++n)
            bfr[n] = *(const short8*)&Bs[cur][(wc * 64 + n * 16 + lrow) * 32 + rchunk];
#pragma unroll
        for (int m = 0; m < 4; ++m)
#pragma unroll
            for (int n = 0; n < 4; ++n)
                acc[m][n] = __builtin_amdgcn_mfma_f32_16x16x32_bf16(af[m], bfr[n], acc[m][n], 0, 0, 0);
        __syncthreads();
        cur ^= 1;
    }

    // ---- LDS-transpose epilogue: dwordx4 C-stores ----
    unsigned short* Ts = &As[0][0];
    float bias4[4];
#pragma unroll
    for (int n = 0; n < 4; ++n) bias4[n] = bias_cat[bcol0 + wc * 64 + n * 16 + lrow];
    const int lrw = wr * 16 + kb * 4;
    const int lcw = wc * 64 + lrow;
#pragma unroll
    for (int m = 0; m < 4; ++m) {
        __syncthreads();
#pragma unroll
        for (int n = 0; n < 4; ++n)
#pragma unroll
            for (int v = 0; v < 4; ++v)
                Ts[(lrw + v) * 132 + lcw + n * 16] = f2bf(acc[m][n][v] + bias4[n]);
        __syncthreads();
#pragma unroll
        for (int rd = 0; rd < 2; ++rd) {
            const int lr = (t >> 4) + rd * 16;          // 0..31
            const int c0 = (t & 15) * 8;                // 0..120 step 8
            const int grow = brow0 + (lr >> 4) * 64 + m * 16 + (lr & 15);
            if (grow < N_NODES) {
                const uint2 lo = *(const uint2*)&Ts[lr * 132 + c0];
                const uint2 hi = *(const uint2*)&Ts[lr * 132 + c0 + 4];
                const uint4 o = make_uint4(lo.x, lo.y, hi.x, hi.y);
                *(uint4*)&Ccat[(size_t)grow * NCAT + bcol0 + c0] = o;
            }
        }
    }
}

// ---- fused edge pass: one wave per target, packed-src CSR walk (round-10 text). ----
__global__ __launch_bounds__(256) void edge_fused(const unsigned short* __restrict__ Ccat,
                                                  const int* __restrict__ off,
                                                  const int* __restrict__ perm,
                                                  unsigned short* __restrict__ Acat) {
    const int wid = threadIdx.x >> 6, lane = threadIdx.x & 63;
    const int tgt = (blockIdx.x << 2) + wid;
    const int h = lane >> 4, f0 = (lane & 15) << 2;
    const int off0 = off[tgt];
    const int off1 = (tgt == N_NODES - 1) ? TE : off[tgt + 1];
    const ushort4 qu = *(const ushort4*)(Ccat + (size_t)tgt * NCAT + 1280 + (h << 6) + f0);
    const float qx = bf2f(qu.x), qy = bf2f(qu.y), qz = bf2f(qu.z), qw = bf2f(qu.w);
    const int voff = 1536 + (h << 6) + f0;
    float es = 0.f;
    float4 a0 = make_float4(0, 0, 0, 0), a1 = a0, a2 = a0, a3 = a0, a4 = a0;
    int i = off0;
    while (i < off1) {
        const bool two = (i + 1 < off1);
        const int pk0 = perm[i];
        const int pk1 = two ? perm[i + 1] : pk0;
        const int s0 = pk0 & 0xFFFF, t0 = pk0 >> 16;
        const int s1 = pk1 & 0xFFFF, t1 = pk1 >> 16;
        const size_t rb0 = (size_t)s0 * NCAT, rb1 = (size_t)s1 * NCAT;
        // issue all 4 gathers before any compute (2x memory-level parallelism)
        const ushort4 ku0 = *(const ushort4*)(Ccat + rb0 + ((t0 * 4 + h) << 6) + f0);
        const ushort4 vu0 = *(const ushort4*)(Ccat + rb0 + voff);
        const ushort4 ku1 = *(const ushort4*)(Ccat + rb1 + ((t1 * 4 + h) << 6) + f0);
        const ushort4 vu1 = *(const ushort4*)(Ccat + rb1 + voff);
        float p0 = qx * bf2f(ku0.x) + qy * bf2f(ku0.y) + qz * bf2f(ku0.z) + qw * bf2f(ku0.w);
        float p1 = qx * bf2f(ku1.x) + qy * bf2f(ku1.y) + qz * bf2f(ku1.z) + qw * bf2f(ku1.w);
        p0 += __shfl_xor(p0, 1); p1 += __shfl_xor(p1, 1);
        p0 += __shfl_xor(p0, 2); p1 += __shfl_xor(p1, 2);
        p0 += __shfl_xor(p0, 4); p1 += __shfl_xor(p1, 4);
        p0 += __shfl_xor(p0, 8); p1 += __shfl_xor(p1, 8);
        {
            const float ex = __expf(p0);
            es += ex;
            const float mx = ex * bf2f(vu0.x), my = ex * bf2f(vu0.y);
            const float mz = ex * bf2f(vu0.z), mw = ex * bf2f(vu0.w);
            if (t0 == 0)      { a0.x += mx; a0.y += my; a0.z += mz; a0.w += mw; }
            else if (t0 == 1) { a1.x += mx; a1.y += my; a1.z += mz; a1.w += mw; }
            else if (t0 == 2) { a2.x += mx; a2.y += my; a2.z += mz; a2.w += mw; }
            else if (t0 == 3) { a3.x += mx; a3.y += my; a3.z += mz; a3.w += mw; }
            else              { a4.x += mx; a4.y += my; a4.z += mz; a4.w += mw; }
        }
        if (two) {
            const float ex = __expf(p1);
            es += ex;
            const float mx = ex * bf2f(vu1.x), my = ex * bf2f(vu1.y);
            const float mz = ex * bf2f(vu1.z), mw = ex * bf2f(vu1.w);
            if (t1 == 0)      { a0.x += mx; a0.y += my; a0.z += mz; a0.w += mw; }
            else if (t1 == 1) { a1.x += mx; a1.y += my; a1.z += mz; a1.w += mw; }
            else if (t1 == 2) { a2.x += mx; a2.y += my; a2.z += mz; a2.w += mw; }
            else if (t1 == 3) { a3.x += mx; a3.y += my; a3.z += mz; a3.w += mw; }
            else              { a4.x += mx; a4.y += my; a4.z += mz; a4.w += mw; }
        }
        i += two ? 2 : 1;
    }
    const float inv = 1.f / (es + 1e-16f);
    const size_t rr = (size_t)tgt * NHEAD + h;
    unsigned short* base = Acat + rr * (NTYPES * HDIM) + f0;
    ushort4 u;
    u.x = f2bf(a0.x * inv); u.y = f2bf(a0.y * inv); u.z = f2bf(a0.z * inv); u.w = f2bf(a0.w * inv);
    *(ushort4*)(base + 0 * HDIM) = u;
    u.x = f2bf(a1.x * inv); u.y = f2bf(a1.y * inv); u.z = f2bf(a1.z * inv); u.w = f2bf(a1.w * inv);
    *(ushort4*)(base + 1 * HDIM) = u;
    u.x = f2bf(a2.x * inv); u.y = f2bf(a2.y * inv); u.z = f2bf(a2.z * inv); u.w = f2bf(a2.w * inv);
    *(ushort4*)(base + 2 * HDIM) = u;
    u.x = f2bf(a3.x * inv); u.y = f2bf(a3.y * inv); u.z = f2bf(a3.z * inv); u.w = f2bf(a3.w * inv);
    *(ushort4*)(base + 3 * HDIM) = u;
    u.x = f2bf(a4.x * inv); u.y = f2bf(a4.y * inv); u.z = f2bf(a4.z * inv); u.w = f2bf(a4.w * inv);
    *(ushort4*)(base + 4 * HDIM) = u;
}

// ---- FUSED TAIL: per 128 nodes: G = gelu(Acat[512rows,320]@vrelT^T) -> LDS(bf16);
//      out[128,256] = sa*(G @ Wob^T + out_b) + sb*hb.   512 threads, 8 waves.
// Phase-1 = gemm_cat compute (proven), output to LDS Gs[128][264] (stride 264: 2-way banks, free).
// Phase-2 = gemm_out compute (proven): A-frags read DIRECTLY from Gs; B = Wob via swizzled
// gload16 dbuf (mfma_gemm's proven stage/read pair). LDS aliasing: As1(40KB) inside Gs(66KB)
// region (dead before Gs written, barrier-separated); Bs1(5KB) inside phase-2 dbuf region.
__global__ __launch_bounds__(512) void tail_fused(const unsigned short* __restrict__ Acat,
                                                  const unsigned short* __restrict__ vrelT,
                                                  const unsigned short* __restrict__ Wob,
                                                  const float* __restrict__ bias,
                                                  float* __restrict__ C,
                                                  const unsigned short* __restrict__ hres,
                                                  const float* __restrict__ skip) {
    __shared__ unsigned short GsAs[128 * 264];   // Gs; first 512*40=20480 aliased as As1 in phase 1
    __shared__ unsigned short Pb[2][256 * 32];   // phase-2 Wob dbuf; first 64*40=2560 aliased as Bs1
    const int t = threadIdx.x;
    const int wid = t >> 6, lane = t & 63;
    const int lrow = lane & 15, kb = lane >> 4;
    const int n0 = blockIdx.x * 128;             // first node of block
    const size_t ar0 = (size_t)n0 * 4;           // first Acat row

    // ================= phase 1: G = gelu(Acat @ vrelT^T) -> Gs =================
    {
        unsigned short* As1 = GsAs;              // [512][40]
        unsigned short* Bs1 = &Pb[0][0];         // [64][40]
        const int r0 = t >> 2, q0 = (t & 3) * 8;
        f32x4 acc[4][4];
#pragma unroll
        for (int m = 0; m < 4; ++m)
#pragma unroll
            for (int n = 0; n < 4; ++n) acc[m][n] = (f32x4)0.f;

        for (int kt = 0; kt < 320; kt += 32) {
            uint4 a[4];
#pragma unroll
            for (int i = 0; i < 4; ++i) {
                const size_t row = min(ar0 + r0 + 128 * i, (size_t)120000 - 1);
                a[i] = *(const uint4*)(Acat + row * 320 + kt + q0);
            }
            uint4 b0;
            if (t < 256) b0 = *(const uint4*)(vrelT + (size_t)r0 * 320 + kt + q0);
            __syncthreads();
#pragma unroll
            for (int i = 0; i < 4; ++i)
                *(uint4*)&As1[(r0 + 128 * i) * 40 + q0] = a[i];
            if (t < 256) *(uint4*)&Bs1[r0 * 40 + q0] = b0;
            __syncthreads();
            short8 af[4], bf_[4];
#pragma unroll
            for (int m = 0; m < 4; ++m)
                af[m] = *(const short8*)&As1[(wid * 64 + m * 16 + lrow) * 40 + kb * 8];
#pragma unroll
            for (int n = 0; n < 4; ++n)
                bf_[n] = *(const short8*)&Bs1[(n * 16 + lrow) * 40 + kb * 8];
#pragma unroll
            for (int m = 0; m < 4; ++m)
#pragma unroll
                for (int n = 0; n < 4; ++n)
                    acc[m][n] = __builtin_amdgcn_mfma_f32_16x16x32_bf16(af[m], bf_[n], acc[m][n], 0, 0, 0);
            __syncthreads();   // all frag reads done before next-step As1 overwrite (and final Gs write)
        }
        // write gelu(acc) into Gs[node_local][hh*64 + col]  (As1 region now dead)
#pragma unroll
        for (int m = 0; m < 4; ++m)
#pragma unroll
            for (int v = 0; v < 4; ++v) {
                const int lr = wid * 64 + m * 16 + kb * 4 + v;   // local Acat row 0..511
#pragma unroll
                for (int n = 0; n < 4; ++n) {
                    const int col = n * 16 + lrow;
                    const float x = acc[m][n][v];
                    const float g = 0.5f * x * (1.f + erff(x * 0.7071067811865475f));
                    GsAs[(lr >> 2) * 264 + (lr & 3) * 64 + col] = f2bf(g);
                }
            }
        __syncthreads();       // Gs complete (also: all Bs1 reads done before Pb staging)
    }

    // ================= phase 2: out = sa*(G @ Wob^T + b) + sb*hb =================
    {
        const int wr = wid >> 2, wc = wid & 3;   // 2 x 4 wave grid: 64-row x 64-col tiles
        const int rchunk = (kb ^ ((lrow >> 1) & 3)) * 8;
        auto stage2 = [&](int buf, int kt) {
#pragma unroll
            for (int j = 0; j < 2; ++j) {
                const int rowbase = (wid + 8 * j) * 16;          // 16 Wob rows per wave-iter
                const int srow = rowbase + (lane >> 2);
                const int gq = ((lane & 3) ^ ((lane >> 3) & 3)) * 8;
                gload16(Wob + (size_t)srow * 256 + kt + gq, &Pb[buf][rowbase * 32]);
            }
        };
        f32x4 acc[4][4];
#pragma unroll
        for (int m = 0; m < 4; ++m)
#pragma unroll
            for (int n = 0; n < 4; ++n) acc[m][n] = (f32x4)0.f;

        stage2(0, 0);
        __syncthreads();
        int cur = 0;
        for (int kt = 0; kt < 256; kt += 32) {
            if (kt + 32 < 256) stage2(cur ^ 1, kt + 32);
            short8 af[4], bfr[4];
#pragma unroll
            for (int m = 0; m < 4; ++m)
                af[m] = *(const short8*)&GsAs[(wr * 64 + m * 16 + lrow) * 264 + kt + kb * 8];
#pragma unroll
            for (int n = 0; n < 4; ++n)
                bfr[n] = *(const short8*)&Pb[cur][(wc * 64 + n * 16 + lrow) * 32 + rchunk];
#pragma unroll
            for (int m = 0; m < 4; ++m)
#pragma unroll
                for (int n = 0; n < 4; ++n)
                    acc[m][n] = __builtin_amdgcn_mfma_f32_16x16x32_bf16(af[m], bfr[n], acc[m][n], 0, 0, 0);
            __syncthreads();
            cur ^= 1;
        }

        const float s = skip[0];
        const float sa = 1.f / (1.f + expf(-s));
        const float sb = 1.f - sa;
        float bias4[4];
#pragma unroll
        for (int n = 0; n < 4; ++n) bias4[n] = bias[wc * 64 + n * 16 + lrow];
#pragma unroll
        for (int m = 0; m < 4; ++m) {
            const int gr0 = n0 + wr * 64 + m * 16 + kb * 4;
#pragma unroll
            for (int v = 0; v < 4; ++v) {
                const int grow = gr0 + v;
                if (grow < N_NODES) {
#pragma unroll
                    for (int n = 0; n < 4; ++n) {
                        const int gcol = wc * 64 + n * 16 + lrow;
                        const float val = acc[m][n][v] + bias4[n];
                        C[(size_t)grow * 256 + gcol] = sa * val + sb * bf2f(hres[(size_t)grow * 256 + gcol]);
                    }
                }
            }
        }
    }
}

extern "C" void kernel_launch(void* const* d_in, const int* in_sizes, int n_in,
                              void* d_out, int out_size, void* d_ws, size_t ws_size,
                              hipStream_t stream) {
    const float* h      = (const float*)d_in[0];
    const int*   esrc   = (const int*)d_in[1];
    const int*   etgt   = (const int*)d_in[2];
    const float* kqv_w  = (const float*)d_in[3];
    const float* kqv_b  = (const float*)d_in[4];
    const float* out_w  = (const float*)d_in[5];
    const float* out_b  = (const float*)d_in[6];
    const float* k_rel  = (const float*)d_in[7];
    const float* v_rel  = (const float*)d_in[8];
    const float* skip   = (const float*)d_in[9];
    const float* p_rel  = (const float*)d_in[10];
    float* out = (float*)d_out;

    // workspace layout (float-sized slots):
    float* ws = (float*)d_ws;
    unsigned short* Ccat     = (unsigned short*)ws;                 // 26,880,000 slots [0 .. 26.88M)
    int*            deg      = (int*)(ws + 26880000);               //     30,000 -> 26,910,000
    int*            off      = (int*)(ws + 26910000);               //     30,000 -> 26,940,000
    int*            cursor   = (int*)(ws + 26940000);               //     30,000 -> 26,970,000
    int*            perm     = (int*)(ws + 26970000);               //    200,000 -> 27,170,000
    unsigned short* Acat     = (unsigned short*)(ws + 31010000);    // 19,200,000 slots -> 50,210,000
    // LATE-READ buffers (consumed AFTER Acat is written) -> past Acat's end:
    unsigned short* vrelT    = (unsigned short*)(ws + 50210000);    // 10,240 slots -> 50,220,240
    unsigned short* Wob      = (unsigned short*)(ws + 50220240);    // 32,768 slots -> 50,253,008
    unsigned short* hb       = (unsigned short*)(ws + 50253008);    // 3,840,000 slots -> 54,093,008
    int*            bsum     = (int*)(ws + 54093008);               //        118 -> 54,093,126
    int*            boff     = (int*)(ws + 54093126);               //        118 -> 54,093,244
    // EARLY-DEAD aliases inside Acat's span (read only BEFORE edge_fused writes Acat):
    unsigned short* Wcat     = (unsigned short*)(ws + 45370000);    // 229,376 slots -> ends 45,599,376
    float*          bias_cat = ws + 45600000;                       // 1,792 -> ends 45,601,792 (< 50.21M ok)
    // total footprint: 54,093,244 float slots = 216.4 MB (round 3 proved >= 219.9 MB available)

    hipLaunchKernelGGL(init_kernel, dim3(NBLK), dim3(256), 0, stream, deg);
    hipLaunchKernelGGL(hist_kernel, dim3(782), dim3(256), 0, stream, etgt, deg);
    hipLaunchKernelGGL(scan1_kernel, dim3(NBLK), dim3(256), 0, stream, deg, bsum);
    hipLaunchKernelGGL(scan2_kernel, dim3(1), dim3(128), 0, stream, bsum, boff);
    hipLaunchKernelGGL(scan3_kernel, dim3(NBLK), dim3(256), 0, stream, deg, boff, off, cursor);
    hipLaunchKernelGGL(scatter_kernel, dim3(782), dim3(256), 0, stream, etgt, esrc, cursor, perm);
    hipLaunchKernelGGL(prep_all, dim3(9628), dim3(256), 0, stream,
                       kqv_w, kqv_b, k_rel, p_rel, h, v_rel, out_w,
                       Wcat, bias_cat, hb, vrelT, Wob);
    hipLaunchKernelGGL(mfma_gemm, dim3(3290), dim3(256), 0, stream,
                       hb, Wcat, bias_cat, Ccat);
    hipLaunchKernelGGL(edge_fused, dim3(N_NODES / 4), dim3(256), 0, stream,
                       Ccat, off, perm, Acat);
    hipLaunchKernelGGL(tail_fused, dim3(235), dim3(512), 0, stream,
                       Acat, vrelT, Wob, out_b, out, hb, skip);
}

// Round 15
// 190.868 us; speedup vs baseline: 1.2320x; 1.0402x over previous
//
#include <hip/hip_runtime.h>
#include <hip/hip_bf16.h>
#include <math.h>

#define N_NODES 30000
#define NHEAD   4
#define HDIM    64
#define NTYPES  5
#define EPT     40000
#define TE      (NTYPES * EPT)
#define KDIM    256
#define NCAT    1792   // 1280 Ktil | 256 Q | 256 V
#define NBLK    118    // ceil(30000/256)

typedef __attribute__((ext_vector_type(8))) short short8;
typedef __attribute__((ext_vector_type(4))) float f32x4;

__device__ __forceinline__ unsigned short f2bf(float f) {
    __hip_bfloat16 h = __float2bfloat16(f);
    return *reinterpret_cast<unsigned short*>(&h);
}
__device__ __forceinline__ float bf2f(unsigned short u) {
    return __uint_as_float((unsigned)u << 16);
}

// async global->LDS, 16B per lane. LDS dest is wave-uniform base + lane*16 (linear).
__device__ __forceinline__ void gload16(const unsigned short* g, unsigned short* l) {
    __builtin_amdgcn_global_load_lds((const __attribute__((address_space(1))) void*)g,
                                     (__attribute__((address_space(3))) void*)l, 16, 0, 0);
}

// ---- init: zero deg ----
__global__ __launch_bounds__(256) void init_kernel(int* __restrict__ deg) {
    const int gid = blockIdx.x * blockDim.x + threadIdx.x;
    if (gid < N_NODES) deg[gid] = 0;
}

// ---- CSR build: histogram ----
__global__ __launch_bounds__(256) void hist_kernel(const int* __restrict__ etgt,
                                                   int* __restrict__ deg) {
    const int stride = gridDim.x * blockDim.x;
    for (int i = blockIdx.x * blockDim.x + threadIdx.x; i < TE; i += stride)
        atomicAdd(&deg[etgt[i]], 1);
}

// ---- hierarchical scan, stage 1: per-block sums (coalesced) ----
__global__ __launch_bounds__(256) void scan1_kernel(const int* __restrict__ deg,
                                                    int* __restrict__ bsum) {
    __shared__ int ws[4];
    const int t = threadIdx.x;
    const int gid = blockIdx.x * 256 + t;
    int d = (gid < N_NODES) ? deg[gid] : 0;
    d += __shfl_xor(d, 1);
    d += __shfl_xor(d, 2);
    d += __shfl_xor(d, 4);
    d += __shfl_xor(d, 8);
    d += __shfl_xor(d, 16);
    d += __shfl_xor(d, 32);
    if ((t & 63) == 0) ws[t >> 6] = d;
    __syncthreads();
    if (t == 0) bsum[blockIdx.x] = ws[0] + ws[1] + ws[2] + ws[3];
}

// ---- hierarchical scan, stage 2: exclusive scan of 118 block sums (1 block) ----
__global__ __launch_bounds__(128) void scan2_kernel(const int* __restrict__ bsum,
                                                    int* __restrict__ boff) {
    __shared__ int s[128];
    const int t = threadIdx.x;
    s[t] = (t < NBLK) ? bsum[t] : 0;
    __syncthreads();
    for (int d = 1; d < 128; d <<= 1) {
        const int v = (t >= d) ? s[t - d] : 0;
        __syncthreads();
        s[t] += v;
        __syncthreads();
    }
    if (t < NBLK) boff[t] = (t > 0) ? s[t - 1] : 0;
}

// ---- hierarchical scan, stage 3: in-block exclusive scan + block base (coalesced) ----
__global__ __launch_bounds__(256) void scan3_kernel(const int* __restrict__ deg,
                                                    const int* __restrict__ boff,
                                                    int* __restrict__ off,
                                                    int* __restrict__ cursor) {
    __shared__ int s[256];
    const int t = threadIdx.x;
    const int gid = blockIdx.x * 256 + t;
    const int d = (gid < N_NODES) ? deg[gid] : 0;
    s[t] = d;
    __syncthreads();
    for (int dd = 1; dd < 256; dd <<= 1) {
        const int v = (t >= dd) ? s[t - dd] : 0;
        __syncthreads();
        s[t] += v;
        __syncthreads();
    }
    if (gid < N_NODES) {
        const int excl = s[t] - d + boff[blockIdx.x];
        off[gid] = excl;
        cursor[gid] = excl;
    }
}

// ---- CSR build: scatter PACKED (src | t<<16) into per-target buckets ----
__global__ __launch_bounds__(256) void scatter_kernel(const int* __restrict__ etgt,
                                                      const int* __restrict__ esrc,
                                                      int* __restrict__ cursor,
                                                      int* __restrict__ perm) {
    const int stride = gridDim.x * blockDim.x;
    for (int e = blockIdx.x * blockDim.x + threadIdx.x; e < TE; e += stride) {
        const int pos = atomicAdd(&cursor[etgt[e]], 1);
        perm[pos] = esrc[e] | ((e / EPT) << 16);
    }
}

// ---- merged prep: [0,1792) weight_prep | [1792,9292) h2bf | [9292,9372) vrelT | [9372,9628) owb ----
__global__ __launch_bounds__(256) void prep_all(const float* __restrict__ kqv_w,
                                                const float* __restrict__ kqv_b,
                                                const float* __restrict__ k_rel,
                                                const float* __restrict__ p_rel,
                                                const float* __restrict__ h,
                                                const float* __restrict__ v_rel,
                                                const float* __restrict__ out_w,
                                                unsigned short* __restrict__ Wcat,
                                                float* __restrict__ bias_cat,
                                                unsigned short* __restrict__ hb,
                                                unsigned short* __restrict__ vrelT,
                                                unsigned short* __restrict__ Wob) {
    const int bid = blockIdx.x;
    const int tid = threadIdx.x;
    if (bid < 1792) {
        const int r = bid, f = tid;
        if (r < 1280) {
            const int t = r >> 8, hh = (r >> 6) & 3, d = r & 63;
            const float sc = 0.125f * p_rel[t * NHEAD + hh];
            float acc = 0.f;
#pragma unroll
            for (int fp = 0; fp < 64; ++fp)
                acc = fmaf(kqv_w[(size_t)(hh * 64 + fp) * 256 + f], k_rel[t * 4096 + fp * 64 + d], acc);
            Wcat[(size_t)r * 256 + f] = f2bf(acc * sc);
            if (f == 0) {
                float b = 0.f;
#pragma unroll
                for (int fp = 0; fp < 64; ++fp)
                    b = fmaf(kqv_b[hh * 64 + fp], k_rel[t * 4096 + fp * 64 + d], b);
                bias_cat[r] = b * sc;
            }
        } else {
            const int src_row = r - 1024;  // 1280->256 (Q), 1536->512 (V)
            Wcat[(size_t)r * 256 + f] = f2bf(kqv_w[(size_t)src_row * 256 + f]);
            if (f == 0) bias_cat[r] = kqv_b[src_row];
        }
    } else if (bid < 9292) {
        const int i = (bid - 1792) * 256 + tid;   // exactly 1,920,000 float4s
        const float4 v = ((const float4*)h)[i];
        ushort4 u;
        u.x = f2bf(v.x); u.y = f2bf(v.y); u.z = f2bf(v.z); u.w = f2bf(v.w);
        ((ushort4*)hb)[i] = u;
    } else if (bid < 9372) {
        const int idx = (bid - 9292) * 256 + tid;
        if (idx < 64 * 320) {
            const int f = idx / 320, k = idx - f * 320;
            vrelT[f * 320 + k] = f2bf(v_rel[(k >> 6) * 4096 + (k & 63) * 64 + f]);
        }
    } else {
        const int i = (bid - 9372) * 256 + tid;   // exactly 65,536
        Wob[i] = f2bf(out_w[i]);
    }
}

// ---- MFMA GEMM: Ccat[30000,1792](bf16) = hb[30000,256] @ Wcat^T + bias_cat ----
__global__ __launch_bounds__(256) void mfma_gemm(const unsigned short* __restrict__ hb,
                                                 const unsigned short* __restrict__ Wcat,
                                                 const float* __restrict__ bias_cat,
                                                 unsigned short* __restrict__ Ccat) {
    __shared__ unsigned short As[2][128 * 32];
    __shared__ unsigned short Bs[2][128 * 32];
    // bijective chunked swizzle over 3290 = 235*14 blocks, 8 XCDs (m204)
    const int orig = blockIdx.x;
    const int xcd = orig & 7, pos = orig >> 3;
    const int q = 3290 / 8, r = 3290 % 8;  // 411, 2
    const int wgid = (xcd < r ? xcd * (q + 1) : r * (q + 1) + (xcd - r) * q) + pos;
    const int brow0 = (wgid / 14) * 128;
    const int bcol0 = (wgid % 14) * 128;

    const int t = threadIdx.x;
    const int wid = t >> 6, lane = t & 63;
    const int wr = wid >> 1, wc = wid & 1;
    const int lrow = lane & 15, kb = lane >> 4;
    const int srow = lane >> 2;
    const int schunk = ((lane & 3) ^ ((lane >> 3) & 3)) * 8;   // staged (swizzled) chunk
    const int rchunk = (kb ^ ((lrow >> 1) & 3)) * 8;           // swizzled read chunk

    const int arow0 = min(brow0 + wid * 16 + srow, N_NODES - 1);
    const int arow1 = min(brow0 + 64 + wid * 16 + srow, N_NODES - 1);
    const int brw0 = bcol0 + wid * 16 + srow;        // always < 1792
    const int brw1 = bcol0 + 64 + wid * 16 + srow;

    auto stage = [&](int buf, int kt) {
        gload16(hb + (size_t)arow0 * KDIM + kt + schunk, &As[buf][wid * 512]);
        gload16(hb + (size_t)arow1 * KDIM + kt + schunk, &As[buf][2048 + wid * 512]);
        gload16(Wcat + (size_t)brw0 * KDIM + kt + schunk, &Bs[buf][wid * 512]);
        gload16(Wcat + (size_t)brw1 * KDIM + kt + schunk, &Bs[buf][2048 + wid * 512]);
    };

    f32x4 acc[4][4];
#pragma unroll
    for (int m = 0; m < 4; ++m)
#pragma unroll
        for (int n = 0; n < 4; ++n) acc[m][n] = (f32x4)0.f;

    stage(0, 0);
    __syncthreads();
    int cur = 0;
    for (int kt = 0; kt < KDIM; kt += 32) {
        if (kt + 32 < KDIM) stage(cur ^ 1, kt + 32);
        short8 af[4], bfr[4];
#pragma unroll
        for (int m = 0; m < 4; ++m)
            af[m] = *(const short8*)&As[cur][(wr * 64 + m * 16 + lrow) * 32 + rchunk];
#pragma unroll
        for (int n = 0; n < 4; ++n)
            bfr[n] = *(const short8*)&Bs[cur][(wc * 64 + n * 16 + lrow) * 32 + rchunk];
#pragma unroll
        for (int m = 0; m < 4; ++m)
#pragma unroll
            for (int n = 0; n < 4; ++n)
                acc[m][n] = __builtin_amdgcn_mfma_f32_16x16x32_bf16(af[m], bfr[n], acc[m][n], 0, 0, 0);
        __syncthreads();
        cur ^= 1;
    }

    // ---- LDS-transpose epilogue: dwordx4 C-stores ----
    unsigned short* Ts = &As[0][0];
    float bias4[4];
#pragma unroll
    for (int n = 0; n < 4; ++n) bias4[n] = bias_cat[bcol0 + wc * 64 + n * 16 + lrow];
    const int lrw = wr * 16 + kb * 4;
    const int lcw = wc * 64 + lrow;
#pragma unroll
    for (int m = 0; m < 4; ++m) {
        __syncthreads();
#pragma unroll
        for (int n = 0; n < 4; ++n)
#pragma unroll
            for (int v = 0; v < 4; ++v)
                Ts[(lrw + v) * 132 + lcw + n * 16] = f2bf(acc[m][n][v] + bias4[n]);
        __syncthreads();
#pragma unroll
        for (int rd = 0; rd < 2; ++rd) {
            const int lr = (t >> 4) + rd * 16;          // 0..31
            const int c0 = (t & 15) * 8;                // 0..120 step 8
            const int grow = brow0 + (lr >> 4) * 64 + m * 16 + (lr & 15);
            if (grow < N_NODES) {
                const uint2 lo = *(const uint2*)&Ts[lr * 132 + c0];
                const uint2 hi = *(const uint2*)&Ts[lr * 132 + c0 + 4];
                const uint4 o = make_uint4(lo.x, lo.y, hi.x, hi.y);
                *(uint4*)&Ccat[(size_t)grow * NCAT + bcol0 + c0] = o;
            }
        }
    }
}

// ---- fused edge pass: one wave per target, packed-src CSR walk (round-10 text). ----
__global__ __launch_bounds__(256) void edge_fused(const unsigned short* __restrict__ Ccat,
                                                  const int* __restrict__ off,
                                                  const int* __restrict__ perm,
                                                  unsigned short* __restrict__ Acat) {
    const int wid = threadIdx.x >> 6, lane = threadIdx.x & 63;
    const int tgt = (blockIdx.x << 2) + wid;
    const int h = lane >> 4, f0 = (lane & 15) << 2;
    const int off0 = off[tgt];
    const int off1 = (tgt == N_NODES - 1) ? TE : off[tgt + 1];
    const ushort4 qu = *(const ushort4*)(Ccat + (size_t)tgt * NCAT + 1280 + (h << 6) + f0);
    const float qx = bf2f(qu.x), qy = bf2f(qu.y), qz = bf2f(qu.z), qw = bf2f(qu.w);
    const int voff = 1536 + (h << 6) + f0;
    float es = 0.f;
    float4 a0 = make_float4(0, 0, 0, 0), a1 = a0, a2 = a0, a3 = a0, a4 = a0;
    int i = off0;
    while (i < off1) {
        const bool two = (i + 1 < off1);
        const int pk0 = perm[i];
        const int pk1 = two ? perm[i + 1] : pk0;
        const int s0 = pk0 & 0xFFFF, t0 = pk0 >> 16;
        const int s1 = pk1 & 0xFFFF, t1 = pk1 >> 16;
        const size_t rb0 = (size_t)s0 * NCAT, rb1 = (size_t)s1 * NCAT;
        // issue all 4 gathers before any compute (2x memory-level parallelism)
        const ushort4 ku0 = *(const ushort4*)(Ccat + rb0 + ((t0 * 4 + h) << 6) + f0);
        const ushort4 vu0 = *(const ushort4*)(Ccat + rb0 + voff);
        const ushort4 ku1 = *(const ushort4*)(Ccat + rb1 + ((t1 * 4 + h) << 6) + f0);
        const ushort4 vu1 = *(const ushort4*)(Ccat + rb1 + voff);
        float p0 = qx * bf2f(ku0.x) + qy * bf2f(ku0.y) + qz * bf2f(ku0.z) + qw * bf2f(ku0.w);
        float p1 = qx * bf2f(ku1.x) + qy * bf2f(ku1.y) + qz * bf2f(ku1.z) + qw * bf2f(ku1.w);
        p0 += __shfl_xor(p0, 1); p1 += __shfl_xor(p1, 1);
        p0 += __shfl_xor(p0, 2); p1 += __shfl_xor(p1, 2);
        p0 += __shfl_xor(p0, 4); p1 += __shfl_xor(p1, 4);
        p0 += __shfl_xor(p0, 8); p1 += __shfl_xor(p1, 8);
        {
            const float ex = __expf(p0);
            es += ex;
            const float mx = ex * bf2f(vu0.x), my = ex * bf2f(vu0.y);
            const float mz = ex * bf2f(vu0.z), mw = ex * bf2f(vu0.w);
            if (t0 == 0)      { a0.x += mx; a0.y += my; a0.z += mz; a0.w += mw; }
            else if (t0 == 1) { a1.x += mx; a1.y += my; a1.z += mz; a1.w += mw; }
            else if (t0 == 2) { a2.x += mx; a2.y += my; a2.z += mz; a2.w += mw; }
            else if (t0 == 3) { a3.x += mx; a3.y += my; a3.z += mz; a3.w += mw; }
            else              { a4.x += mx; a4.y += my; a4.z += mz; a4.w += mw; }
        }
        if (two) {
            const float ex = __expf(p1);
            es += ex;
            const float mx = ex * bf2f(vu1.x), my = ex * bf2f(vu1.y);
            const float mz = ex * bf2f(vu1.z), mw = ex * bf2f(vu1.w);
            if (t1 == 0)      { a0.x += mx; a0.y += my; a0.z += mz; a0.w += mw; }
            else if (t1 == 1) { a1.x += mx; a1.y += my; a1.z += mz; a1.w += mw; }
            else if (t1 == 2) { a2.x += mx; a2.y += my; a2.z += mz; a2.w += mw; }
            else if (t1 == 3) { a3.x += mx; a3.y += my; a3.z += mz; a3.w += mw; }
            else              { a4.x += mx; a4.y += my; a4.z += mz; a4.w += mw; }
        }
        i += two ? 2 : 1;
    }
    const float inv = 1.f / (es + 1e-16f);
    const size_t rr = (size_t)tgt * NHEAD + h;
    unsigned short* base = Acat + rr * (NTYPES * HDIM) + f0;
    ushort4 u;
    u.x = f2bf(a0.x * inv); u.y = f2bf(a0.y * inv); u.z = f2bf(a0.z * inv); u.w = f2bf(a0.w * inv);
    *(ushort4*)(base + 0 * HDIM) = u;
    u.x = f2bf(a1.x * inv); u.y = f2bf(a1.y * inv); u.z = f2bf(a1.z * inv); u.w = f2bf(a1.w * inv);
    *(ushort4*)(base + 1 * HDIM) = u;
    u.x = f2bf(a2.x * inv); u.y = f2bf(a2.y * inv); u.z = f2bf(a2.z * inv); u.w = f2bf(a2.w * inv);
    *(ushort4*)(base + 2 * HDIM) = u;
    u.x = f2bf(a3.x * inv); u.y = f2bf(a3.y * inv); u.z = f2bf(a3.z * inv); u.w = f2bf(a3.w * inv);
    *(ushort4*)(base + 3 * HDIM) = u;
    u.x = f2bf(a4.x * inv); u.y = f2bf(a4.y * inv); u.z = f2bf(a4.z * inv); u.w = f2bf(a4.w * inv);
    *(ushort4*)(base + 4 * HDIM) = u;
}

// ---- FUSED TAIL v2: 64 nodes/block, 256 threads (4 waves), grid 469.
// Phase-1 = gemm_cat_mfma's proven 256-row geometry, gelu output to LDS Gs[64][264] (bf16).
// Phase-2 = gemm_out compute: A-frags from Gs; B = Wob via swizzled gload16 dbuf.
// LDS 66.5 KB -> 2 blocks/CU (round 14's 133 KB/1-block shape was the regression).
__global__ __launch_bounds__(256) void tail_fused(const unsigned short* __restrict__ Acat,
                                                  const unsigned short* __restrict__ vrelT,
                                                  const unsigned short* __restrict__ Wob,
                                                  const float* __restrict__ bias,
                                                  float* __restrict__ C,
                                                  const unsigned short* __restrict__ hres,
                                                  const float* __restrict__ skip) {
    __shared__ unsigned short GsAs[64 * 264];    // Gs 33.8KB; first 256*40=10240 ushorts aliased as As1
    __shared__ unsigned short Pb[2][256 * 32];   // phase-2 Wob dbuf 32KB; first 64*40 aliased as Bs1
    const int t = threadIdx.x;
    const int wid = t >> 6, lane = t & 63;
    const int lrow = lane & 15, kb = lane >> 4;
    const int n0 = blockIdx.x * 64;              // first node of block
    const size_t ar0 = (size_t)n0 * 4;           // first Acat row (256 rows per block)

    // ================= phase 1: G = gelu(Acat @ vrelT^T) -> Gs =================
    {
        unsigned short* As1 = GsAs;              // [256][40]
        unsigned short* Bs1 = &Pb[0][0];         // [64][40]
        const int r0 = t >> 2, q0 = (t & 3) * 8;
        f32x4 acc[4][4];
#pragma unroll
        for (int m = 0; m < 4; ++m)
#pragma unroll
            for (int n = 0; n < 4; ++n) acc[m][n] = (f32x4)0.f;

        for (int kt = 0; kt < 320; kt += 32) {
            uint4 a[4];
#pragma unroll
            for (int i = 0; i < 4; ++i) {
                const size_t row = min(ar0 + r0 + 64 * i, (size_t)120000 - 1);
                a[i] = *(const uint4*)(Acat + row * 320 + kt + q0);
            }
            const uint4 b0 = *(const uint4*)(vrelT + (size_t)r0 * 320 + kt + q0);
            __syncthreads();
#pragma unroll
            for (int i = 0; i < 4; ++i)
                *(uint4*)&As1[(r0 + 64 * i) * 40 + q0] = a[i];
            *(uint4*)&Bs1[r0 * 40 + q0] = b0;
            __syncthreads();
            short8 af[4], bf_[4];
#pragma unroll
            for (int m = 0; m < 4; ++m)
                af[m] = *(const short8*)&As1[(wid * 64 + m * 16 + lrow) * 40 + kb * 8];
#pragma unroll
            for (int n = 0; n < 4; ++n)
                bf_[n] = *(const short8*)&Bs1[(n * 16 + lrow) * 40 + kb * 8];
#pragma unroll
            for (int m = 0; m < 4; ++m)
#pragma unroll
                for (int n = 0; n < 4; ++n)
                    acc[m][n] = __builtin_amdgcn_mfma_f32_16x16x32_bf16(af[m], bf_[n], acc[m][n], 0, 0, 0);
            __syncthreads();   // frag reads done before next As1 overwrite / final Gs write
        }
        // write gelu(acc) into Gs (As1 region now dead)
#pragma unroll
        for (int m = 0; m < 4; ++m)
#pragma unroll
            for (int v = 0; v < 4; ++v) {
                const int lr = wid * 64 + m * 16 + kb * 4 + v;   // local Acat row 0..255
#pragma unroll
                for (int n = 0; n < 4; ++n) {
                    const int col = n * 16 + lrow;
                    const float x = acc[m][n][v];
                    const float g = 0.5f * x * (1.f + erff(x * 0.7071067811865475f));
                    GsAs[(lr >> 2) * 264 + (lr & 3) * 64 + col] = f2bf(g);
                }
            }
        __syncthreads();       // Gs complete; Bs1 reads done before Pb staging
    }

    // ================= phase 2: out[64,256] = sa*(G @ Wob^T + b) + sb*hb =================
    {
        const int wc = wid;                      // each wave owns one 64-col tile
        const int srow = lane >> 2;
        const int schunk = ((lane & 3) ^ ((lane >> 3) & 3)) * 8;
        const int rchunk = (kb ^ ((lrow >> 1) & 3)) * 8;
        auto stage2 = [&](int buf, int kt) {
#pragma unroll
            for (int j = 0; j < 4; ++j) {
                const int rowbase = j * 64 + wid * 16;           // 64-row sweep per gload16
                gload16(Wob + (size_t)(rowbase + srow) * 256 + kt + schunk,
                        &Pb[buf][rowbase * 32]);
            }
        };
        f32x4 acc[4][4];
#pragma unroll
        for (int m = 0; m < 4; ++m)
#pragma unroll
            for (int n = 0; n < 4; ++n) acc[m][n] = (f32x4)0.f;

        stage2(0, 0);
        __syncthreads();
        int cur = 0;
        for (int kt = 0; kt < 256; kt += 32) {
            if (kt + 32 < 256) stage2(cur ^ 1, kt + 32);
            short8 af[4], bfr[4];
#pragma unroll
            for (int m = 0; m < 4; ++m)
                af[m] = *(const short8*)&GsAs[(m * 16 + lrow) * 264 + kt + kb * 8];
#pragma unroll
            for (int n = 0; n < 4; ++n)
                bfr[n] = *(const short8*)&Pb[cur][(wc * 64 + n * 16 + lrow) * 32 + rchunk];
#pragma unroll
            for (int m = 0; m < 4; ++m)
#pragma unroll
                for (int n = 0; n < 4; ++n)
                    acc[m][n] = __builtin_amdgcn_mfma_f32_16x16x32_bf16(af[m], bfr[n], acc[m][n], 0, 0, 0);
            __syncthreads();
            cur ^= 1;
        }

        const float s = skip[0];
        const float sa = 1.f / (1.f + expf(-s));
        const float sb = 1.f - sa;
        float bias4[4];
#pragma unroll
        for (int n = 0; n < 4; ++n) bias4[n] = bias[wc * 64 + n * 16 + lrow];
#pragma unroll
        for (int m = 0; m < 4; ++m) {
            const int gr0 = n0 + m * 16 + kb * 4;
#pragma unroll
            for (int v = 0; v < 4; ++v) {
                const int grow = gr0 + v;
                if (grow < N_NODES) {
#pragma unroll
                    for (int n = 0; n < 4; ++n) {
                        const int gcol = wc * 64 + n * 16 + lrow;
                        const float val = acc[m][n][v] + bias4[n];
                        C[(size_t)grow * 256 + gcol] = sa * val + sb * bf2f(hres[(size_t)grow * 256 + gcol]);
                    }
                }
            }
        }
    }
}

extern "C" void kernel_launch(void* const* d_in, const int* in_sizes, int n_in,
                              void* d_out, int out_size, void* d_ws, size_t ws_size,
                              hipStream_t stream) {
    const float* h      = (const float*)d_in[0];
    const int*   esrc   = (const int*)d_in[1];
    const int*   etgt   = (const int*)d_in[2];
    const float* kqv_w  = (const float*)d_in[3];
    const float* kqv_b  = (const float*)d_in[4];
    const float* out_w  = (const float*)d_in[5];
    const float* out_b  = (const float*)d_in[6];
    const float* k_rel  = (const float*)d_in[7];
    const float* v_rel  = (const float*)d_in[8];
    const float* skip   = (const float*)d_in[9];
    const float* p_rel  = (const float*)d_in[10];
    float* out = (float*)d_out;

    // workspace layout (float-sized slots):
    float* ws = (float*)d_ws;
    unsigned short* Ccat     = (unsigned short*)ws;                 // 26,880,000 slots [0 .. 26.88M)
    int*            deg      = (int*)(ws + 26880000);               //     30,000 -> 26,910,000
    int*            off      = (int*)(ws + 26910000);               //     30,000 -> 26,940,000
    int*            cursor   = (int*)(ws + 26940000);               //     30,000 -> 26,970,000
    int*            perm     = (int*)(ws + 26970000);               //    200,000 -> 27,170,000
    unsigned short* Acat     = (unsigned short*)(ws + 31010000);    // 19,200,000 slots -> 50,210,000
    // LATE-READ buffers (consumed AFTER Acat is written) -> past Acat's end:
    unsigned short* vrelT    = (unsigned short*)(ws + 50210000);    // 10,240 slots -> 50,220,240
    unsigned short* Wob      = (unsigned short*)(ws + 50220240);    // 32,768 slots -> 50,253,008
    unsigned short* hb       = (unsigned short*)(ws + 50253008);    // 3,840,000 slots -> 54,093,008
    int*            bsum     = (int*)(ws + 54093008);               //        118 -> 54,093,126
    int*            boff     = (int*)(ws + 54093126);               //        118 -> 54,093,244
    // EARLY-DEAD aliases inside Acat's span (read only BEFORE edge_fused writes Acat):
    unsigned short* Wcat     = (unsigned short*)(ws + 45370000);    // 229,376 slots -> ends 45,599,376
    float*          bias_cat = ws + 45600000;                       // 1,792 -> ends 45,601,792 (< 50.21M ok)
    // total footprint: 54,093,244 float slots = 216.4 MB (round 3 proved >= 219.9 MB available)

    hipLaunchKernelGGL(init_kernel, dim3(NBLK), dim3(256), 0, stream, deg);
    hipLaunchKernelGGL(hist_kernel, dim3(782), dim3(256), 0, stream, etgt, deg);
    hipLaunchKernelGGL(scan1_kernel, dim3(NBLK), dim3(256), 0, stream, deg, bsum);
    hipLaunchKernelGGL(scan2_kernel, dim3(1), dim3(128), 0, stream, bsum, boff);
    hipLaunchKernelGGL(scan3_kernel, dim3(NBLK), dim3(256), 0, stream, deg, boff, off, cursor);
    hipLaunchKernelGGL(scatter_kernel, dim3(782), dim3(256), 0, stream, etgt, esrc, cursor, perm);
    hipLaunchKernelGGL(prep_all, dim3(9628), dim3(256), 0, stream,
                       kqv_w, kqv_b, k_rel, p_rel, h, v_rel, out_w,
                       Wcat, bias_cat, hb, vrelT, Wob);
    hipLaunchKernelGGL(mfma_gemm, dim3(3290), dim3(256), 0, stream,
                       hb, Wcat, bias_cat, Ccat);
    hipLaunchKernelGGL(edge_fused, dim3(N_NODES / 4), dim3(256), 0, stream,
                       Ccat, off, perm, Acat);
    hipLaunchKernelGGL(tail_fused, dim3(469), dim3(256), 0, stream,
                       Acat, vrelT, Wob, out_b, out, hb, skip);
}

// Round 16
// 176.983 us; speedup vs baseline: 1.3286x; 1.0785x over previous
//
#include <hip/hip_runtime.h>
#include <hip/hip_bf16.h>
#include <math.h>

#define N_NODES 30000
#define NHEAD   4
#define HDIM    64
#define NTYPES  5
#define EPT     40000
#define TE      (NTYPES * EPT)
#define KDIM    256
#define NCAT    1792   // 1280 Ktil | 256 Q | 256 V
#define NBLK    118    // ceil(30000/256)

typedef __attribute__((ext_vector_type(8))) short short8;
typedef __attribute__((ext_vector_type(4))) float f32x4;

__device__ __forceinline__ unsigned short f2bf(float f) {
    __hip_bfloat16 h = __float2bfloat16(f);
    return *reinterpret_cast<unsigned short*>(&h);
}
__device__ __forceinline__ float bf2f(unsigned short u) {
    return __uint_as_float((unsigned)u << 16);
}

// async global->LDS, 16B per lane. LDS dest is wave-uniform base + lane*16 (linear).
__device__ __forceinline__ void gload16(const unsigned short* g, unsigned short* l) {
    __builtin_amdgcn_global_load_lds((const __attribute__((address_space(1))) void*)g,
                                     (__attribute__((address_space(3))) void*)l, 16, 0, 0);
}

// ---- init: zero deg ----
__global__ __launch_bounds__(256) void init_kernel(int* __restrict__ deg) {
    const int gid = blockIdx.x * blockDim.x + threadIdx.x;
    if (gid < N_NODES) deg[gid] = 0;
}

// ---- CSR build: histogram ----
__global__ __launch_bounds__(256) void hist_kernel(const int* __restrict__ etgt,
                                                   int* __restrict__ deg) {
    const int stride = gridDim.x * blockDim.x;
    for (int i = blockIdx.x * blockDim.x + threadIdx.x; i < TE; i += stride)
        atomicAdd(&deg[etgt[i]], 1);
}

// ---- hierarchical scan, stage 1: per-block sums (coalesced) ----
__global__ __launch_bounds__(256) void scan1_kernel(const int* __restrict__ deg,
                                                    int* __restrict__ bsum) {
    __shared__ int ws[4];
    const int t = threadIdx.x;
    const int gid = blockIdx.x * 256 + t;
    int d = (gid < N_NODES) ? deg[gid] : 0;
    d += __shfl_xor(d, 1);
    d += __shfl_xor(d, 2);
    d += __shfl_xor(d, 4);
    d += __shfl_xor(d, 8);
    d += __shfl_xor(d, 16);
    d += __shfl_xor(d, 32);
    if ((t & 63) == 0) ws[t >> 6] = d;
    __syncthreads();
    if (t == 0) bsum[blockIdx.x] = ws[0] + ws[1] + ws[2] + ws[3];
}

// ---- hierarchical scan, stage 2: exclusive scan of 118 block sums (1 block) ----
__global__ __launch_bounds__(128) void scan2_kernel(const int* __restrict__ bsum,
                                                    int* __restrict__ boff) {
    __shared__ int s[128];
    const int t = threadIdx.x;
    s[t] = (t < NBLK) ? bsum[t] : 0;
    __syncthreads();
    for (int d = 1; d < 128; d <<= 1) {
        const int v = (t >= d) ? s[t - d] : 0;
        __syncthreads();
        s[t] += v;
        __syncthreads();
    }
    if (t < NBLK) boff[t] = (t > 0) ? s[t - 1] : 0;
}

// ---- hierarchical scan, stage 3: in-block exclusive scan + block base (coalesced) ----
__global__ __launch_bounds__(256) void scan3_kernel(const int* __restrict__ deg,
                                                    const int* __restrict__ boff,
                                                    int* __restrict__ off,
                                                    int* __restrict__ cursor) {
    __shared__ int s[256];
    const int t = threadIdx.x;
    const int gid = blockIdx.x * 256 + t;
    const int d = (gid < N_NODES) ? deg[gid] : 0;
    s[t] = d;
    __syncthreads();
    for (int dd = 1; dd < 256; dd <<= 1) {
        const int v = (t >= dd) ? s[t - dd] : 0;
        __syncthreads();
        s[t] += v;
        __syncthreads();
    }
    if (gid < N_NODES) {
        const int excl = s[t] - d + boff[blockIdx.x];
        off[gid] = excl;
        cursor[gid] = excl;
    }
}

// ---- CSR build: scatter PACKED (src | t<<16) into per-target buckets ----
__global__ __launch_bounds__(256) void scatter_kernel(const int* __restrict__ etgt,
                                                      const int* __restrict__ esrc,
                                                      int* __restrict__ cursor,
                                                      int* __restrict__ perm) {
    const int stride = gridDim.x * blockDim.x;
    for (int e = blockIdx.x * blockDim.x + threadIdx.x; e < TE; e += stride) {
        const int pos = atomicAdd(&cursor[etgt[e]], 1);
        perm[pos] = esrc[e] | ((e / EPT) << 16);
    }
}

// ---- merged prep: [0,1792) weight_prep | [1792,9292) h2bf | [9292,9372) vrelT | [9372,9628) owb ----
__global__ __launch_bounds__(256) void prep_all(const float* __restrict__ kqv_w,
                                                const float* __restrict__ kqv_b,
                                                const float* __restrict__ k_rel,
                                                const float* __restrict__ p_rel,
                                                const float* __restrict__ h,
                                                const float* __restrict__ v_rel,
                                                const float* __restrict__ out_w,
                                                unsigned short* __restrict__ Wcat,
                                                float* __restrict__ bias_cat,
                                                unsigned short* __restrict__ hb,
                                                unsigned short* __restrict__ vrelT,
                                                unsigned short* __restrict__ Wob) {
    const int bid = blockIdx.x;
    const int tid = threadIdx.x;
    if (bid < 1792) {
        const int r = bid, f = tid;
        if (r < 1280) {
            const int t = r >> 8, hh = (r >> 6) & 3, d = r & 63;
            const float sc = 0.125f * p_rel[t * NHEAD + hh];
            float acc = 0.f;
#pragma unroll
            for (int fp = 0; fp < 64; ++fp)
                acc = fmaf(kqv_w[(size_t)(hh * 64 + fp) * 256 + f], k_rel[t * 4096 + fp * 64 + d], acc);
            Wcat[(size_t)r * 256 + f] = f2bf(acc * sc);
            if (f == 0) {
                float b = 0.f;
#pragma unroll
                for (int fp = 0; fp < 64; ++fp)
                    b = fmaf(kqv_b[hh * 64 + fp], k_rel[t * 4096 + fp * 64 + d], b);
                bias_cat[r] = b * sc;
            }
        } else {
            const int src_row = r - 1024;  // 1280->256 (Q), 1536->512 (V)
            Wcat[(size_t)r * 256 + f] = f2bf(kqv_w[(size_t)src_row * 256 + f]);
            if (f == 0) bias_cat[r] = kqv_b[src_row];
        }
    } else if (bid < 9292) {
        const int i = (bid - 1792) * 256 + tid;   // exactly 1,920,000 float4s
        const float4 v = ((const float4*)h)[i];
        ushort4 u;
        u.x = f2bf(v.x); u.y = f2bf(v.y); u.z = f2bf(v.z); u.w = f2bf(v.w);
        ((ushort4*)hb)[i] = u;
    } else if (bid < 9372) {
        const int idx = (bid - 9292) * 256 + tid;
        if (idx < 64 * 320) {
            const int f = idx / 320, k = idx - f * 320;
            vrelT[f * 320 + k] = f2bf(v_rel[(k >> 6) * 4096 + (k & 63) * 64 + f]);
        }
    } else {
        const int i = (bid - 9372) * 256 + tid;   // exactly 65,536
        Wob[i] = f2bf(out_w[i]);
    }
}

// ---- MFMA GEMM: Ccat[30000,1792](bf16) = hb[30000,256] @ Wcat^T + bias_cat ----
__global__ __launch_bounds__(256) void mfma_gemm(const unsigned short* __restrict__ hb,
                                                 const unsigned short* __restrict__ Wcat,
                                                 const float* __restrict__ bias_cat,
                                                 unsigned short* __restrict__ Ccat) {
    __shared__ unsigned short As[2][128 * 32];
    __shared__ unsigned short Bs[2][128 * 32];
    // bijective chunked swizzle over 3290 = 235*14 blocks, 8 XCDs (m204)
    const int orig = blockIdx.x;
    const int xcd = orig & 7, pos = orig >> 3;
    const int q = 3290 / 8, r = 3290 % 8;  // 411, 2
    const int wgid = (xcd < r ? xcd * (q + 1) : r * (q + 1) + (xcd - r) * q) + pos;
    const int brow0 = (wgid / 14) * 128;
    const int bcol0 = (wgid % 14) * 128;

    const int t = threadIdx.x;
    const int wid = t >> 6, lane = t & 63;
    const int wr = wid >> 1, wc = wid & 1;
    const int lrow = lane & 15, kb = lane >> 4;
    const int srow = lane >> 2;
    const int schunk = ((lane & 3) ^ ((lane >> 3) & 3)) * 8;   // staged (swizzled) chunk
    const int rchunk = (kb ^ ((lrow >> 1) & 3)) * 8;           // swizzled read chunk

    const int arow0 = min(brow0 + wid * 16 + srow, N_NODES - 1);
    const int arow1 = min(brow0 + 64 + wid * 16 + srow, N_NODES - 1);
    const int brw0 = bcol0 + wid * 16 + srow;        // always < 1792
    const int brw1 = bcol0 + 64 + wid * 16 + srow;

    auto stage = [&](int buf, int kt) {
        gload16(hb + (size_t)arow0 * KDIM + kt + schunk, &As[buf][wid * 512]);
        gload16(hb + (size_t)arow1 * KDIM + kt + schunk, &As[buf][2048 + wid * 512]);
        gload16(Wcat + (size_t)brw0 * KDIM + kt + schunk, &Bs[buf][wid * 512]);
        gload16(Wcat + (size_t)brw1 * KDIM + kt + schunk, &Bs[buf][2048 + wid * 512]);
    };

    f32x4 acc[4][4];
#pragma unroll
    for (int m = 0; m < 4; ++m)
#pragma unroll
        for (int n = 0; n < 4; ++n) acc[m][n] = (f32x4)0.f;

    stage(0, 0);
    __syncthreads();
    int cur = 0;
    for (int kt = 0; kt < KDIM; kt += 32) {
        if (kt + 32 < KDIM) stage(cur ^ 1, kt + 32);
        short8 af[4], bfr[4];
#pragma unroll
        for (int m = 0; m < 4; ++m)
            af[m] = *(const short8*)&As[cur][(wr * 64 + m * 16 + lrow) * 32 + rchunk];
#pragma unroll
        for (int n = 0; n < 4; ++n)
            bfr[n] = *(const short8*)&Bs[cur][(wc * 64 + n * 16 + lrow) * 32 + rchunk];
#pragma unroll
        for (int m = 0; m < 4; ++m)
#pragma unroll
            for (int n = 0; n < 4; ++n)
                acc[m][n] = __builtin_amdgcn_mfma_f32_16x16x32_bf16(af[m], bfr[n], acc[m][n], 0, 0, 0);
        __syncthreads();
        cur ^= 1;
    }

    // ---- LDS-transpose epilogue: dwordx4 C-stores ----
    unsigned short* Ts = &As[0][0];
    float bias4[4];
#pragma unroll
    for (int n = 0; n < 4; ++n) bias4[n] = bias_cat[bcol0 + wc * 64 + n * 16 + lrow];
    const int lrw = wr * 16 + kb * 4;
    const int lcw = wc * 64 + lrow;
#pragma unroll
    for (int m = 0; m < 4; ++m) {
        __syncthreads();
#pragma unroll
        for (int n = 0; n < 4; ++n)
#pragma unroll
            for (int v = 0; v < 4; ++v)
                Ts[(lrw + v) * 132 + lcw + n * 16] = f2bf(acc[m][n][v] + bias4[n]);
        __syncthreads();
#pragma unroll
        for (int rd = 0; rd < 2; ++rd) {
            const int lr = (t >> 4) + rd * 16;          // 0..31
            const int c0 = (t & 15) * 8;                // 0..120 step 8
            const int grow = brow0 + (lr >> 4) * 64 + m * 16 + (lr & 15);
            if (grow < N_NODES) {
                const uint2 lo = *(const uint2*)&Ts[lr * 132 + c0];
                const uint2 hi = *(const uint2*)&Ts[lr * 132 + c0 + 4];
                const uint4 o = make_uint4(lo.x, lo.y, hi.x, hi.y);
                *(uint4*)&Ccat[(size_t)grow * NCAT + bcol0 + c0] = o;
            }
        }
    }
}

// ---- fused edge pass: one wave per target, packed-src CSR walk (round-10 text). ----
__global__ __launch_bounds__(256) void edge_fused(const unsigned short* __restrict__ Ccat,
                                                  const int* __restrict__ off,
                                                  const int* __restrict__ perm,
                                                  unsigned short* __restrict__ Acat) {
    const int wid = threadIdx.x >> 6, lane = threadIdx.x & 63;
    const int tgt = (blockIdx.x << 2) + wid;
    const int h = lane >> 4, f0 = (lane & 15) << 2;
    const int off0 = off[tgt];
    const int off1 = (tgt == N_NODES - 1) ? TE : off[tgt + 1];
    const ushort4 qu = *(const ushort4*)(Ccat + (size_t)tgt * NCAT + 1280 + (h << 6) + f0);
    const float qx = bf2f(qu.x), qy = bf2f(qu.y), qz = bf2f(qu.z), qw = bf2f(qu.w);
    const int voff = 1536 + (h << 6) + f0;
    float es = 0.f;
    float4 a0 = make_float4(0, 0, 0, 0), a1 = a0, a2 = a0, a3 = a0, a4 = a0;
    int i = off0;
    while (i < off1) {
        const bool two = (i + 1 < off1);
        const int pk0 = perm[i];
        const int pk1 = two ? perm[i + 1] : pk0;
        const int s0 = pk0 & 0xFFFF, t0 = pk0 >> 16;
        const int s1 = pk1 & 0xFFFF, t1 = pk1 >> 16;
        const size_t rb0 = (size_t)s0 * NCAT, rb1 = (size_t)s1 * NCAT;
        // issue all 4 gathers before any compute (2x memory-level parallelism)
        const ushort4 ku0 = *(const ushort4*)(Ccat + rb0 + ((t0 * 4 + h) << 6) + f0);
        const ushort4 vu0 = *(const ushort4*)(Ccat + rb0 + voff);
        const ushort4 ku1 = *(const ushort4*)(Ccat + rb1 + ((t1 * 4 + h) << 6) + f0);
        const ushort4 vu1 = *(const ushort4*)(Ccat + rb1 + voff);
        float p0 = qx * bf2f(ku0.x) + qy * bf2f(ku0.y) + qz * bf2f(ku0.z) + qw * bf2f(ku0.w);
        float p1 = qx * bf2f(ku1.x) + qy * bf2f(ku1.y) + qz * bf2f(ku1.z) + qw * bf2f(ku1.w);
        p0 += __shfl_xor(p0, 1); p1 += __shfl_xor(p1, 1);
        p0 += __shfl_xor(p0, 2); p1 += __shfl_xor(p1, 2);
        p0 += __shfl_xor(p0, 4); p1 += __shfl_xor(p1, 4);
        p0 += __shfl_xor(p0, 8); p1 += __shfl_xor(p1, 8);
        {
            const float ex = __expf(p0);
            es += ex;
            const float mx = ex * bf2f(vu0.x), my = ex * bf2f(vu0.y);
            const float mz = ex * bf2f(vu0.z), mw = ex * bf2f(vu0.w);
            if (t0 == 0)      { a0.x += mx; a0.y += my; a0.z += mz; a0.w += mw; }
            else if (t0 == 1) { a1.x += mx; a1.y += my; a1.z += mz; a1.w += mw; }
            else if (t0 == 2) { a2.x += mx; a2.y += my; a2.z += mz; a2.w += mw; }
            else if (t0 == 3) { a3.x += mx; a3.y += my; a3.z += mz; a3.w += mw; }
            else              { a4.x += mx; a4.y += my; a4.z += mz; a4.w += mw; }
        }
        if (two) {
            const float ex = __expf(p1);
            es += ex;
            const float mx = ex * bf2f(vu1.x), my = ex * bf2f(vu1.y);
            const float mz = ex * bf2f(vu1.z), mw = ex * bf2f(vu1.w);
            if (t1 == 0)      { a0.x += mx; a0.y += my; a0.z += mz; a0.w += mw; }
            else if (t1 == 1) { a1.x += mx; a1.y += my; a1.z += mz; a1.w += mw; }
            else if (t1 == 2) { a2.x += mx; a2.y += my; a2.z += mz; a2.w += mw; }
            else if (t1 == 3) { a3.x += mx; a3.y += my; a3.z += mz; a3.w += mw; }
            else              { a4.x += mx; a4.y += my; a4.z += mz; a4.w += mw; }
        }
        i += two ? 2 : 1;
    }
    const float inv = 1.f / (es + 1e-16f);
    const size_t rr = (size_t)tgt * NHEAD + h;
    unsigned short* base = Acat + rr * (NTYPES * HDIM) + f0;
    ushort4 u;
    u.x = f2bf(a0.x * inv); u.y = f2bf(a0.y * inv); u.z = f2bf(a0.z * inv); u.w = f2bf(a0.w * inv);
    *(ushort4*)(base + 0 * HDIM) = u;
    u.x = f2bf(a1.x * inv); u.y = f2bf(a1.y * inv); u.z = f2bf(a1.z * inv); u.w = f2bf(a1.w * inv);
    *(ushort4*)(base + 1 * HDIM) = u;
    u.x = f2bf(a2.x * inv); u.y = f2bf(a2.y * inv); u.z = f2bf(a2.z * inv); u.w = f2bf(a2.w * inv);
    *(ushort4*)(base + 2 * HDIM) = u;
    u.x = f2bf(a3.x * inv); u.y = f2bf(a3.y * inv); u.z = f2bf(a3.z * inv); u.w = f2bf(a3.w * inv);
    *(ushort4*)(base + 3 * HDIM) = u;
    u.x = f2bf(a4.x * inv); u.y = f2bf(a4.y * inv); u.z = f2bf(a4.z * inv); u.w = f2bf(a4.w * inv);
    *(ushort4*)(base + 4 * HDIM) = u;
}

// ---- FUSED TAIL v3: 64 nodes/block, 256 threads (4 waves), grid 469. BARRIER-FREE loops.
// Key insight: A-operands have zero inter-wave reuse (each wave owns its 64 rows) and
// B-operands (vrelT 40KB, Wob 128KB) are L2-resident -> read BOTH directly in MFMA
// fragment layout from global; no LDS staging, no K-loop barriers. Only Gs (gelu
// intermediate, 33.8KB) uses LDS -> 4 blocks/CU, compiler pipelines K-loop freely.
__global__ __launch_bounds__(256) void tail_fused(const unsigned short* __restrict__ Acat,
                                                  const unsigned short* __restrict__ vrelT,
                                                  const unsigned short* __restrict__ Wob,
                                                  const float* __restrict__ bias,
                                                  float* __restrict__ C,
                                                  const unsigned short* __restrict__ hres,
                                                  const float* __restrict__ skip) {
    __shared__ unsigned short Gs[64 * 264];      // gelu intermediate, stride 264 (2-way banks, free)
    const int t = threadIdx.x;
    const int wid = t >> 6, lane = t & 63;
    const int lrow = lane & 15, kb = lane >> 4;
    const int n0 = blockIdx.x * 64;              // first node of block
    const size_t ar0 = (size_t)n0 * 4;           // first Acat row (256 rows per block)

    // ================= phase 1: G = gelu(Acat @ vrelT^T) -> Gs (no barriers in loop) ====
    {
        f32x4 acc[4][4];
#pragma unroll
        for (int m = 0; m < 4; ++m)
#pragma unroll
            for (int n = 0; n < 4; ++n) acc[m][n] = (f32x4)0.f;

        // per-lane A row indices (clamped; garbage rows only affect unwritten outputs)
        size_t arow[4];
#pragma unroll
        for (int m = 0; m < 4; ++m)
            arow[m] = min(ar0 + (size_t)(wid * 64 + m * 16 + lrow), (size_t)120000 - 1);

        for (int kt = 0; kt < 320; kt += 32) {
            short8 af[4], bf_[4];
#pragma unroll
            for (int m = 0; m < 4; ++m)
                af[m] = *(const short8*)(Acat + arow[m] * 320 + kt + kb * 8);
#pragma unroll
            for (int n = 0; n < 4; ++n)
                bf_[n] = *(const short8*)(vrelT + (size_t)(n * 16 + lrow) * 320 + kt + kb * 8);
#pragma unroll
            for (int m = 0; m < 4; ++m)
#pragma unroll
                for (int n = 0; n < 4; ++n)
                    acc[m][n] = __builtin_amdgcn_mfma_f32_16x16x32_bf16(af[m], bf_[n], acc[m][n], 0, 0, 0);
        }
        // write gelu(acc) into Gs
#pragma unroll
        for (int m = 0; m < 4; ++m)
#pragma unroll
            for (int v = 0; v < 4; ++v) {
                const int lr = wid * 64 + m * 16 + kb * 4 + v;   // local Acat row 0..255
#pragma unroll
                for (int n = 0; n < 4; ++n) {
                    const int col = n * 16 + lrow;
                    const float x = acc[m][n][v];
                    const float g = 0.5f * x * (1.f + erff(x * 0.7071067811865475f));
                    Gs[(lr >> 2) * 264 + (lr & 3) * 64 + col] = f2bf(g);
                }
            }
    }
    __syncthreads();   // Gs complete — the ONLY barrier

    // ================= phase 2: out[64,256] = sa*(G @ Wob^T + b) + sb*hb (no barriers) ====
    {
        const int wc = wid;                      // each wave owns one 64-col tile
        f32x4 acc[4][4];
#pragma unroll
        for (int m = 0; m < 4; ++m)
#pragma unroll
            for (int n = 0; n < 4; ++n) acc[m][n] = (f32x4)0.f;

        for (int kt = 0; kt < 256; kt += 32) {
            short8 af[4], bfr[4];
#pragma unroll
            for (int m = 0; m < 4; ++m)
                af[m] = *(const short8*)&Gs[(m * 16 + lrow) * 264 + kt + kb * 8];
#pragma unroll
            for (int n = 0; n < 4; ++n)
                bfr[n] = *(const short8*)(Wob + (size_t)(wc * 64 + n * 16 + lrow) * 256 + kt + kb * 8);
#pragma unroll
            for (int m = 0; m < 4; ++m)
#pragma unroll
                for (int n = 0; n < 4; ++n)
                    acc[m][n] = __builtin_amdgcn_mfma_f32_16x16x32_bf16(af[m], bfr[n], acc[m][n], 0, 0, 0);
        }

        const float s = skip[0];
        const float sa = 1.f / (1.f + expf(-s));
        const float sb = 1.f - sa;
        float bias4[4];
#pragma unroll
        for (int n = 0; n < 4; ++n) bias4[n] = bias[wc * 64 + n * 16 + lrow];
#pragma unroll
        for (int m = 0; m < 4; ++m) {
            const int gr0 = n0 + m * 16 + kb * 4;
#pragma unroll
            for (int v = 0; v < 4; ++v) {
                const int grow = gr0 + v;
                if (grow < N_NODES) {
#pragma unroll
                    for (int n = 0; n < 4; ++n) {
                        const int gcol = wc * 64 + n * 16 + lrow;
                        const float val = acc[m][n][v] + bias4[n];
                        C[(size_t)grow * 256 + gcol] = sa * val + sb * bf2f(hres[(size_t)grow * 256 + gcol]);
                    }
                }
            }
        }
    }
}

extern "C" void kernel_launch(void* const* d_in, const int* in_sizes, int n_in,
                              void* d_out, int out_size, void* d_ws, size_t ws_size,
                              hipStream_t stream) {
    const float* h      = (const float*)d_in[0];
    const int*   esrc   = (const int*)d_in[1];
    const int*   etgt   = (const int*)d_in[2];
    const float* kqv_w  = (const float*)d_in[3];
    const float* kqv_b  = (const float*)d_in[4];
    const float* out_w  = (const float*)d_in[5];
    const float* out_b  = (const float*)d_in[6];
    const float* k_rel  = (const float*)d_in[7];
    const float* v_rel  = (const float*)d_in[8];
    const float* skip   = (const float*)d_in[9];
    const float* p_rel  = (const float*)d_in[10];
    float* out = (float*)d_out;

    // workspace layout (float-sized slots):
    float* ws = (float*)d_ws;
    unsigned short* Ccat     = (unsigned short*)ws;                 // 26,880,000 slots [0 .. 26.88M)
    int*            deg      = (int*)(ws + 26880000);               //     30,000 -> 26,910,000
    int*            off      = (int*)(ws + 26910000);               //     30,000 -> 26,940,000
    int*            cursor   = (int*)(ws + 26940000);               //     30,000 -> 26,970,000
    int*            perm     = (int*)(ws + 26970000);               //    200,000 -> 27,170,000
    unsigned short* Acat     = (unsigned short*)(ws + 31010000);    // 19,200,000 slots -> 50,210,000
    // LATE-READ buffers (consumed AFTER Acat is written) -> past Acat's end:
    unsigned short* vrelT    = (unsigned short*)(ws + 50210000);    // 10,240 slots -> 50,220,240
    unsigned short* Wob      = (unsigned short*)(ws + 50220240);    // 32,768 slots -> 50,253,008
    unsigned short* hb       = (unsigned short*)(ws + 50253008);    // 3,840,000 slots -> 54,093,008
    int*            bsum     = (int*)(ws + 54093008);               //        118 -> 54,093,126
    int*            boff     = (int*)(ws + 54093126);               //        118 -> 54,093,244
    // EARLY-DEAD aliases inside Acat's span (read only BEFORE edge_fused writes Acat):
    unsigned short* Wcat     = (unsigned short*)(ws + 45370000);    // 229,376 slots -> ends 45,599,376
    float*          bias_cat = ws + 45600000;                       // 1,792 -> ends 45,601,792 (< 50.21M ok)
    // total footprint: 54,093,244 float slots = 216.4 MB (round 3 proved >= 219.9 MB available)

    hipLaunchKernelGGL(init_kernel, dim3(NBLK), dim3(256), 0, stream, deg);
    hipLaunchKernelGGL(hist_kernel, dim3(782), dim3(256), 0, stream, etgt, deg);
    hipLaunchKernelGGL(scan1_kernel, dim3(NBLK), dim3(256), 0, stream, deg, bsum);
    hipLaunchKernelGGL(scan2_kernel, dim3(1), dim3(128), 0, stream, bsum, boff);
    hipLaunchKernelGGL(scan3_kernel, dim3(NBLK), dim3(256), 0, stream, deg, boff, off, cursor);
    hipLaunchKernelGGL(scatter_kernel, dim3(782), dim3(256), 0, stream, etgt, esrc, cursor, perm);
    hipLaunchKernelGGL(prep_all, dim3(9628), dim3(256), 0, stream,
                       kqv_w, kqv_b, k_rel, p_rel, h, v_rel, out_w,
                       Wcat, bias_cat, hb, vrelT, Wob);
    hipLaunchKernelGGL(mfma_gemm, dim3(3290), dim3(256), 0, stream,
                       hb, Wcat, bias_cat, Ccat);
    hipLaunchKernelGGL(edge_fused, dim3(N_NODES / 4), dim3(256), 0, stream,
                       Ccat, off, perm, Acat);
    hipLaunchKernelGGL(tail_fused, dim3(469), dim3(256), 0, stream,
                       Acat, vrelT, Wob, out_b, out, hb, skip);
}